// Round 1
// baseline (402.478 us; speedup 1.0000x reference)
//
#include <hip/hip_runtime.h>
#include <math.h>

// Problem constants
constexpr int NSUP = 3072;            // B*S images
constexpr int NIMG = 4096;            // B*S + B*Q images
constexpr float EPSF = 1e-5f;

// Workspace layout (float offsets)
constexpr int WS_W1E   = 0;           // 32*36  conv1(x)pool composite 6x6, bn-scaled
constexpr int WS_B1    = 1152;        // 32
constexpr int WS_W2E   = 1184;        // 32*32*12 (padded taps), bn-scaled
constexpr int WS_B2    = 13472;       // 32
constexpr int WS_W3E   = 13504;       // 32*32*12
constexpr int WS_B3    = 25792;       // 32
constexpr int WS_W4E   = 25824;       // 32*12
constexpr int WS_B4    = 26208;       // 1 (+3 pad)
constexpr int WS_ACC   = 26212;       // [0]=loss_sum [1]=n_correct (+2 pad)
constexpr int WS_FEATS = 26216;       // 4096*64

__device__ __forceinline__ float gelu_f(float x) {
    return 0.5f * x * (1.0f + erff(x * 0.70710678118654752440f));
}

// ---------------------------------------------------------------------------
// Precompute: fold BN into conv weights; conv1 composed with the 28->8 avg
// pool (both linear) gives an effective 6x6 filter per channel.
// ---------------------------------------------------------------------------
__global__ void __launch_bounds__(256) precompute_kernel(
    const float* __restrict__ c1w, const float* __restrict__ c1b, const float* __restrict__ bn1,
    const float* __restrict__ c2w, const float* __restrict__ c2b, const float* __restrict__ bn2,
    const float* __restrict__ c3w, const float* __restrict__ c3b, const float* __restrict__ bn3,
    const float* __restrict__ c4w, const float* __restrict__ c4b, const float* __restrict__ bn4,
    float* __restrict__ ws)
{
    const int t = threadIdx.x;
    if (t < 32) {
        const int c = t;
        float sc1 = bn1[c] * rsqrtf(bn1[96 + c] + EPSF);
        ws[WS_B1 + c] = (c1b[c] - bn1[64 + c]) * sc1 + bn1[32 + c];
        for (int tt = 0; tt < 6; ++tt)
            for (int s = 0; s < 6; ++s) {
                float sum = 0.f;
                for (int di = 0; di < 3; ++di) {
                    int a = tt - di; if (a < 0 || a > 3) continue;
                    for (int dj = 0; dj < 3; ++dj) {
                        int bb = s - dj; if (bb < 0 || bb > 3) continue;
                        sum += c1w[c * 9 + di * 3 + dj];
                    }
                }
                ws[WS_W1E + c * 36 + tt * 6 + s] = sum * sc1 * (1.0f / 16.0f);
            }
        float sc2 = bn2[c] * rsqrtf(bn2[96 + c] + EPSF);
        ws[WS_B2 + c] = (c2b[c] - bn2[64 + c]) * sc2 + bn2[32 + c];
        float sc3 = bn3[c] * rsqrtf(bn3[96 + c] + EPSF);
        ws[WS_B3 + c] = (c3b[c] - bn3[64 + c]) * sc3 + bn3[32 + c];
    }
    for (int v = t; v < 9216; v += 256) {
        int oc = v / 288; int rem = v - oc * 288;
        int ic = rem / 9;  int tap = rem - ic * 9;
        float sc2 = bn2[oc] * rsqrtf(bn2[96 + oc] + EPSF);
        ws[WS_W2E + oc * 384 + ic * 12 + tap] = c2w[v] * sc2;
        float sc3 = bn3[oc] * rsqrtf(bn3[96 + oc] + EPSF);
        ws[WS_W3E + oc * 384 + ic * 12 + tap] = c3w[v] * sc3;
    }
    {
        float sc4 = bn4[0] * rsqrtf(bn4[3] + EPSF);
        for (int v = t; v < 288; v += 256) {
            int ic = v / 9; int tap = v - ic * 9;
            ws[WS_W4E + ic * 12 + tap] = c4w[v] * sc4;
        }
        if (t == 0) ws[WS_B4] = (c4b[0] - bn4[2]) * sc4 + bn4[1];
    }
    if (t < 2) ws[WS_ACC + t] = 0.f;
}

// ---------------------------------------------------------------------------
// Per-image conv stack. One block = one image, 256 threads.
// LDS buffers padded: [32 ch][10 rows][stride 12] -> aligned b128 row reads.
// ---------------------------------------------------------------------------
__device__ __forceinline__ void conv_layer(const float* __restrict__ src, float* __restrict__ dst,
                                           const float* __restrict__ wg, const float* __restrict__ betag,
                                           int t)
{
    const int r = t & 7, oc = t >> 3;   // thread: one out-channel, one row, 8 cols
    float acc[8] = {0,0,0,0,0,0,0,0};
    const float* wbase = wg + oc * 384;
    for (int ic = 0; ic < 32; ++ic) {
        const float* ap = src + ic * 120 + r * 12;
        float rw[3][12];
        #pragma unroll
        for (int dr = 0; dr < 3; ++dr) {
            float4 a0 = *(const float4*)(ap + dr * 12);
            float4 a1 = *(const float4*)(ap + dr * 12 + 4);
            float4 a2 = *(const float4*)(ap + dr * 12 + 8);
            rw[dr][0]=a0.x; rw[dr][1]=a0.y; rw[dr][2]=a0.z; rw[dr][3]=a0.w;
            rw[dr][4]=a1.x; rw[dr][5]=a1.y; rw[dr][6]=a1.z; rw[dr][7]=a1.w;
            rw[dr][8]=a2.x; rw[dr][9]=a2.y; rw[dr][10]=a2.z; rw[dr][11]=a2.w;
        }
        const float4* wp = (const float4*)(wbase + ic * 12);
        float4 w0 = wp[0], w1 = wp[1], w2 = wp[2];
        float wv[9] = {w0.x,w0.y,w0.z,w0.w,w1.x,w1.y,w1.z,w1.w,w2.x};
        #pragma unroll
        for (int dr = 0; dr < 3; ++dr)
            #pragma unroll
            for (int dc = 0; dc < 3; ++dc) {
                float w = wv[dr * 3 + dc];
                #pragma unroll
                for (int c = 0; c < 8; ++c)
                    acc[c] += w * rw[dr][c + dc];
            }
    }
    float beta = betag[oc];
    #pragma unroll
    for (int c = 0; c < 8; ++c)
        dst[oc * 120 + (r + 1) * 12 + (c + 1)] = gelu_f(acc[c] + beta);
}

__global__ void __launch_bounds__(256) feats_kernel(
    const float* __restrict__ sxs, const float* __restrict__ qxs,
    const float* __restrict__ lin_w, const float* __restrict__ ws,
    float* __restrict__ feats)
{
    __shared__ __align__(16) float sA[3840];
    __shared__ __align__(16) float sB[3840];
    __shared__ __align__(16) float simg[990];   // 30 rows, stride 33 (bank-stagger)
    __shared__ float sw1[1184];                 // conv1 composite weights + beta
    __shared__ float sh4[64];

    const int t = threadIdx.x;
    const int n = blockIdx.x;
    const float* img = (n < NSUP) ? (sxs + n * 784) : (qxs + (n - NSUP) * 784);

    for (int i = t; i < 3840; i += 256) { sA[i] = 0.f; sB[i] = 0.f; }
    for (int i = t; i < 990; i += 256) simg[i] = 0.f;
    for (int i = t; i < 1184; i += 256) sw1[i] = ws[WS_W1E + i];
    __syncthreads();
    for (int i = t; i < 784; i += 256) {
        int r = i / 28, c = i - r * 28;
        simg[(r + 1) * 33 + (c + 1)] = img[i];
    }
    __syncthreads();

    // Stage 1: conv1+bn1+avgpool(28->8)+gelu as one 6x6 correlation
    {
        const int oc = t >> 3, orow = t & 7;
        const int so = (orow * 7) >> 1;         // pool window starts {0,3,7,10,14,17,21,24}
        float acc[8] = {0,0,0,0,0,0,0,0};
        const float* Wc = sw1 + oc * 36;
        #pragma unroll
        for (int tt = 0; tt < 6; ++tt) {
            const float* irow = simg + (so + tt) * 33;
            #pragma unroll
            for (int s = 0; s < 6; ++s) {
                float w = Wc[tt * 6 + s];
                #pragma unroll
                for (int p = 0; p < 8; ++p)
                    acc[p] += w * irow[((p * 7) >> 1) + s];
            }
        }
        float beta = sw1[1152 + oc];
        #pragma unroll
        for (int p = 0; p < 8; ++p)
            sA[oc * 120 + (orow + 1) * 12 + (p + 1)] = gelu_f(acc[p] + beta);
    }
    __syncthreads();

    conv_layer(sA, sB, ws + WS_W2E, ws + WS_B2, t);   // conv2+bn2+gelu
    __syncthreads();
    conv_layer(sB, sA, ws + WS_W3E, ws + WS_B3, t);   // conv3+bn3+gelu
    __syncthreads();

    // Stage 4: conv4 (32->1) + bn4 + gelu
    if (t < 64) {
        const int r = t >> 3, c = t & 7;
        float acc = 0.f;
        for (int ic = 0; ic < 32; ++ic) {
            const float* ap = sA + ic * 120 + r * 12;
            const float4* wp = (const float4*)(ws + WS_W4E + ic * 12);
            float4 w0 = wp[0], w1 = wp[1], w2 = wp[2];
            float wv[9] = {w0.x,w0.y,w0.z,w0.w,w1.x,w1.y,w1.z,w1.w,w2.x};
            #pragma unroll
            for (int dr = 0; dr < 3; ++dr)
                #pragma unroll
                for (int dc = 0; dc < 3; ++dc)
                    acc += wv[dr * 3 + dc] * ap[dr * 12 + c + dc];
        }
        sh4[t] = gelu_f(acc + ws[WS_B4]);
    }
    __syncthreads();
    // Linear: feat[e] = sum_j h4[j] * lin_w[e, j]
    if (t < 64) {
        const float4* lw = (const float4*)(lin_w + t * 64);
        float acc = 0.f;
        #pragma unroll
        for (int j = 0; j < 16; ++j) {
            float4 w = lw[j];
            acc += w.x * sh4[j*4] + w.y * sh4[j*4+1] + w.z * sh4[j*4+2] + w.w * sh4[j*4+3];
        }
        feats[n * 64 + t] = acc;
    }
}

// ---------------------------------------------------------------------------
// Head: per batch element b, the whole _get_lor + low-rank preds + loss.
// ---------------------------------------------------------------------------
__global__ void __launch_bounds__(256) head_kernel(
    const float* __restrict__ w1, const float* __restrict__ w2,
    const float* __restrict__ emb, const float* __restrict__ tags,
    const float* __restrict__ rq, const float* __restrict__ rk,
    const float* __restrict__ rv, const float* __restrict__ ro,
    const float* __restrict__ lnw, const float* __restrict__ lnb,
    const int* __restrict__ sys, const int* __restrict__ qys,
    const float* __restrict__ feats, float* __restrict__ acc_out)
{
    __shared__ __align__(16) float sW1[4096];   // transposed: [d][e] = w1[e][d]
    __shared__ __align__(16) float sW2[4096];
    __shared__ __align__(16) float sX[1536];    // inp tokens (24 x 64)
    __shared__ __align__(16) float sU[1536];
    __shared__ __align__(16) float sV[1536];
    __shared__ __align__(16) float s_xq[128];
    __shared__ __align__(16) float s_ah[128];
    __shared__ __align__(16) float s_yp[128];
    __shared__ float s_t1[12], s_t2[12], s_mu[24], s_rs[24], s_lg[4];

    const int t = threadIdx.x;
    const int b = blockIdx.x;

    // Stage w1/w2 transposed (conflict-free lane-consecutive reads later)
    for (int v = t; v < 1024; v += 256) {
        int e = v & 63, j = v >> 6;
        float4 g1 = *(const float4*)(w1 + e * 64 + j * 4);
        float4 g2 = *(const float4*)(w2 + e * 64 + j * 4);
        sW1[(j*4+0)*64 + e] = g1.x; sW1[(j*4+1)*64 + e] = g1.y;
        sW1[(j*4+2)*64 + e] = g1.z; sW1[(j*4+3)*64 + e] = g1.w;
        sW2[(j*4+0)*64 + e] = g2.x; sW2[(j*4+1)*64 + e] = g2.y;
        sW2[(j*4+2)*64 + e] = g2.z; sW2[(j*4+3)*64 + e] = g2.w;
    }
    // Build inp tokens: sx + emb[sys] + tags[0..3]
    for (int idx = t; idx < 1536; idx += 256) {
        int k = idx >> 6, e = idx & 63;
        int s = k >> 2, tg = k & 3;
        int cls = sys[b * 6 + s];
        sX[idx] = feats[(b * 6 + s) * 64 + e] + emb[cls * 64 + e] + tags[tg * 64 + e];
    }
    __syncthreads();
    // ah = gelu(X @ w1^T) -> sU
    for (int idx = t; idx < 1536; idx += 256) {
        int k = idx >> 6, e = idx & 63;
        float acc = 0.f;
        #pragma unroll
        for (int j = 0; j < 16; ++j) {
            float4 xv = *(const float4*)(sX + k * 64 + j * 4);
            acc += sW1[(j*4+0)*64+e]*xv.x + sW1[(j*4+1)*64+e]*xv.y
                 + sW1[(j*4+2)*64+e]*xv.z + sW1[(j*4+3)*64+e]*xv.w;
        }
        sU[idx] = gelu_f(acc);
    }
    __syncthreads();
    // q = ah @ w2^T -> sV
    for (int idx = t; idx < 1536; idx += 256) {
        int k = idx >> 6, e = idx & 63;
        float acc = 0.f;
        #pragma unroll
        for (int j = 0; j < 16; ++j) {
            float4 xv = *(const float4*)(sU + k * 64 + j * 4);
            acc += sW2[(j*4+0)*64+e]*xv.x + sW2[(j*4+1)*64+e]*xv.y
                 + sW2[(j*4+2)*64+e]*xv.z + sW2[(j*4+3)*64+e]*xv.w;
        }
        sV[idx] = acc;
    }
    __syncthreads();
    // qh[k][nh] = sum_d r_q[nh][d] * q[k][d] -> sU
    for (int idx = t; idx < 1536; idx += 256) {
        int k = idx >> 6, nh = idx & 63;
        const float4* rp = (const float4*)(rq + nh * 64);
        float acc = 0.f;
        #pragma unroll
        for (int j = 0; j < 16; ++j) {
            float4 rw = rp[j];
            float4 xv = *(const float4*)(sV + k * 64 + j * 4);
            acc += rw.x*xv.x + rw.y*xv.y + rw.z*xv.z + rw.w*xv.w;
        }
        sU[idx] = acc;
    }
    __syncthreads();
    // attention over 16 slots per (k, head) -> lor in sV
    if (t < 96) {
        int k = t >> 2, n = t & 3;
        float qv[16];
        #pragma unroll
        for (int h = 0; h < 16; ++h) qv[h] = sU[k * 64 + n * 16 + h];
        float p[16]; float mx = -1e30f;
        #pragma unroll
        for (int r = 0; r < 16; ++r) {
            const float* rkp = rk + r * 64 + n * 16;
            float d = 0.f;
            #pragma unroll
            for (int h = 0; h < 16; ++h) d += qv[h] * rkp[h];
            d *= 0.25f;
            p[r] = d; mx = fmaxf(mx, d);
        }
        float sum = 0.f;
        #pragma unroll
        for (int r = 0; r < 16; ++r) { p[r] = expf(p[r] - mx); sum += p[r]; }
        float inv = 1.0f / sum;
        #pragma unroll
        for (int h = 0; h < 16; ++h) {
            float a = 0.f;
            #pragma unroll
            for (int r = 0; r < 16; ++r) a += p[r] * rv[r * 64 + n * 16 + h];
            sV[k * 64 + n * 16 + h] = a * inv;
        }
    }
    __syncthreads();
    // z = lor @ r_o + x -> sU
    for (int idx = t; idx < 1536; idx += 256) {
        int k = idx >> 6, e = idx & 63;
        float acc = sX[idx];
        #pragma unroll 8
        for (int d = 0; d < 64; ++d)
            acc += sV[k * 64 + d] * ro[d * 64 + e];
        sU[idx] = acc;
    }
    __syncthreads();
    // LayerNorm stats (two-pass, staggered reads to dodge bank conflicts)
    if (t < 24) {
        float s = 0.f;
        for (int jj = 0; jj < 64; ++jj) { int j = (jj + t) & 63; s += sU[t * 64 + j]; }
        float mu = s * (1.0f / 64.0f);
        float v = 0.f;
        for (int jj = 0; jj < 64; ++jj) {
            int j = (jj + t) & 63;
            float d = sU[t * 64 + j] - mu; v += d * d;
        }
        s_mu[t] = mu;
        s_rs[t] = 1.0f / sqrtf(v * (1.0f / 64.0f) + EPSF);
    }
    __syncthreads();
    for (int idx = t; idx < 1536; idx += 256) {
        int k = idx >> 6, e = idx & 63;
        sU[idx] = (sU[idx] - s_mu[k]) * s_rs[k] * lnw[e] + lnb[e];
    }
    __syncthreads();
    // ---- preds on 2 query tokens with rank-6 updated weights ----
    if (t < 128) {
        int q = t >> 6, e = t & 63;
        s_xq[t] = feats[(NSUP + b * 2 + q) * 64 + e] + tags[4 * 64 + e];
    }
    __syncthreads();
    if (t < 12) {   // t1[q][s] = r1s[s] . xq[q]
        int q = t / 6, s = t - q * 6;
        float d = 0.f;
        for (int dd = 0; dd < 64; ++dd) d += sU[(s * 4 + 1) * 64 + dd] * s_xq[q * 64 + dd];
        s_t1[t] = d;
    }
    __syncthreads();
    if (t < 128) {  // h = w1 xq + sum_s l1s[s] t1[s]; ah = gelu(h)
        int q = t >> 6, e = t & 63;
        float acc = 0.f;
        #pragma unroll
        for (int j = 0; j < 16; ++j) {
            float4 xv = *(const float4*)(s_xq + q * 64 + j * 4);
            acc += sW1[(j*4+0)*64+e]*xv.x + sW1[(j*4+1)*64+e]*xv.y
                 + sW1[(j*4+2)*64+e]*xv.z + sW1[(j*4+3)*64+e]*xv.w;
        }
        #pragma unroll
        for (int s = 0; s < 6; ++s) acc += sU[(s * 4 + 0) * 64 + e] * s_t1[q * 6 + s];
        s_ah[t] = gelu_f(acc);
    }
    __syncthreads();
    if (t < 12) {   // t2[q][s] = r2s[s] . ah[q]
        int q = t / 6, s = t - q * 6;
        float d = 0.f;
        for (int dd = 0; dd < 64; ++dd) d += sU[(s * 4 + 3) * 64 + dd] * s_ah[q * 64 + dd];
        s_t2[t] = d;
    }
    __syncthreads();
    if (t < 128) {  // y = w2 ah + sum_s l2s[s] t2[s]
        int q = t >> 6, e = t & 63;
        float acc = 0.f;
        #pragma unroll
        for (int j = 0; j < 16; ++j) {
            float4 xv = *(const float4*)(s_ah + q * 64 + j * 4);
            acc += sW2[(j*4+0)*64+e]*xv.x + sW2[(j*4+1)*64+e]*xv.y
                 + sW2[(j*4+2)*64+e]*xv.z + sW2[(j*4+3)*64+e]*xv.w;
        }
        #pragma unroll
        for (int s = 0; s < 6; ++s) acc += sU[(s * 4 + 2) * 64 + e] * s_t2[q * 6 + s];
        s_yp[t] = acc;
    }
    __syncthreads();
    if (t < 4) {    // logits[q][l] = emb[l] . y[q]
        int q = t >> 1, l = t & 1;
        float d = 0.f;
        for (int j = 0; j < 64; ++j) d += emb[l * 64 + j] * s_yp[q * 64 + j];
        s_lg[t] = d;
    }
    __syncthreads();
    if (t == 0) {
        float lsum = 0.f, corr = 0.f;
        #pragma unroll
        for (int q = 0; q < 2; ++q) {
            float l0 = s_lg[q * 2], l1 = s_lg[q * 2 + 1];
            int lab = qys[b * 2 + q];
            float m = fmaxf(l0, l1);
            float lse = m + logf(expf(l0 - m) + expf(l1 - m));
            lsum += -((lab ? l1 : l0) - lse);
            int pred = (l1 > l0) ? 1 : 0;
            corr += (pred == lab) ? 1.0f : 0.0f;
        }
        atomicAdd(acc_out + 0, lsum);
        atomicAdd(acc_out + 1, corr);
    }
}

__global__ void finalize_kernel(const float* __restrict__ acc, float* __restrict__ out)
{
    if (threadIdx.x == 0) {
        float loss = acc[0] * (1.0f / 1024.0f);
        out[0] = loss;
        out[1] = loss;
        out[2] = 0.0f;
        out[3] = acc[1];
        out[4] = 1024.0f;
    }
}

extern "C" void kernel_launch(void* const* d_in, const int* in_sizes, int n_in,
                              void* d_out, int out_size, void* d_ws, size_t ws_size,
                              hipStream_t stream)
{
    (void)in_sizes; (void)n_in; (void)out_size; (void)ws_size;
    const float* sxs  = (const float*)d_in[1];
    const float* qxs  = (const float*)d_in[2];
    const float* c1w  = (const float*)d_in[4];
    const float* c1b  = (const float*)d_in[5];
    const float* bn1  = (const float*)d_in[6];
    const float* c2w  = (const float*)d_in[7];
    const float* c2b  = (const float*)d_in[8];
    const float* bn2  = (const float*)d_in[9];
    const float* c3w  = (const float*)d_in[10];
    const float* c3b  = (const float*)d_in[11];
    const float* bn3  = (const float*)d_in[12];
    const float* c4w  = (const float*)d_in[13];
    const float* c4b  = (const float*)d_in[14];
    const float* bn4  = (const float*)d_in[15];
    const float* lin_w= (const float*)d_in[16];
    const float* emb  = (const float*)d_in[17];
    const float* w1   = (const float*)d_in[18];
    const float* w2   = (const float*)d_in[19];
    const float* tags = (const float*)d_in[20];
    const float* rq   = (const float*)d_in[21];
    const float* rk   = (const float*)d_in[22];
    const float* rv   = (const float*)d_in[23];
    const float* ro   = (const float*)d_in[24];
    const float* lnw  = (const float*)d_in[25];
    const float* lnb  = (const float*)d_in[26];
    const int*   sys  = (const int*)d_in[27];
    const int*   qys  = (const int*)d_in[28];

    float* ws  = (float*)d_ws;
    float* out = (float*)d_out;

    precompute_kernel<<<1, 256, 0, stream>>>(c1w, c1b, bn1, c2w, c2b, bn2,
                                             c3w, c3b, bn3, c4w, c4b, bn4, ws);
    feats_kernel<<<NIMG, 256, 0, stream>>>(sxs, qxs, lin_w, ws, ws + WS_FEATS);
    head_kernel<<<512, 256, 0, stream>>>(w1, w2, emb, tags, rq, rk, rv, ro,
                                         lnw, lnb, sys, qys,
                                         ws + WS_FEATS, ws + WS_ACC);
    finalize_kernel<<<1, 64, 0, stream>>>(ws + WS_ACC, out);
}

// Round 2
// 393.966 us; speedup vs baseline: 1.0216x; 1.0216x over previous
//
#include <hip/hip_runtime.h>
#include <math.h>

constexpr int NSUP = 3072;            // B*S images
constexpr float EPSF = 1e-5f;

// Workspace layout (float offsets)
constexpr int WS_W1T  = 0;            // [tap36][oc32] conv1(x)pool composite, bn-scaled
constexpr int WS_B1   = 1152;         // 32
constexpr int WS_W2T  = 1184;         // [ic32][tap9][oc32]
constexpr int WS_B2   = 10400;        // 32
constexpr int WS_W3T  = 10432;        // [ic32][tap9][oc32]
constexpr int WS_B3   = 19648;        // 32
constexpr int WS_W4   = 19680;        // [ic32][tap9]
constexpr int WS_B4   = 19968;        // 1 (+3 pad)
constexpr int WS_PART = 19972;        // [512] loss partials, [512] correct partials
constexpr int WS_FEATS= 20996;        // 4096*64

__device__ __forceinline__ float gelu_f(float x) {
    return 0.5f * x * (1.0f + erff(x * 0.70710678118654752440f));
}

// ---------------------------------------------------------------------------
// Precompute: fold BN into conv weights, emit tap-major (oc-fastest) layouts.
// ---------------------------------------------------------------------------
__global__ void __launch_bounds__(256) precompute_kernel(
    const float* __restrict__ c1w, const float* __restrict__ c1b, const float* __restrict__ bn1,
    const float* __restrict__ c2w, const float* __restrict__ c2b, const float* __restrict__ bn2,
    const float* __restrict__ c3w, const float* __restrict__ c3b, const float* __restrict__ bn3,
    const float* __restrict__ c4w, const float* __restrict__ c4b, const float* __restrict__ bn4,
    float* __restrict__ ws)
{
    const int t = threadIdx.x;
    if (t < 32) {
        const int c = t;
        float sc1 = bn1[c] * rsqrtf(bn1[96 + c] + EPSF);
        ws[WS_B1 + c] = (c1b[c] - bn1[64 + c]) * sc1 + bn1[32 + c];
        float sc2 = bn2[c] * rsqrtf(bn2[96 + c] + EPSF);
        ws[WS_B2 + c] = (c2b[c] - bn2[64 + c]) * sc2 + bn2[32 + c];
        float sc3 = bn3[c] * rsqrtf(bn3[96 + c] + EPSF);
        ws[WS_B3 + c] = (c3b[c] - bn3[64 + c]) * sc3 + bn3[32 + c];
    }
    // conv1 (x) 28->8 avgpool composite 6x6, tap-major [tap][oc]
    for (int v = t; v < 1152; v += 256) {
        int oc = v & 31, tap = v >> 5;
        int tt = tap / 6, s = tap - tt * 6;
        float sum = 0.f;
        for (int di = 0; di < 3; ++di) {
            int a = tt - di; if (a < 0 || a > 3) continue;
            for (int dj = 0; dj < 3; ++dj) {
                int bb = s - dj; if (bb < 0 || bb > 3) continue;
                sum += c1w[oc * 9 + di * 3 + dj];
            }
        }
        float sc1 = bn1[oc] * rsqrtf(bn1[96 + oc] + EPSF);
        ws[WS_W1T + v] = sum * sc1 * (1.0f / 16.0f);
    }
    // conv2/conv3 weights: [ic][tap][oc]
    for (int v = t; v < 9216; v += 256) {
        int oc = v & 31; int r2 = v >> 5;
        int ic = r2 / 9; int tap = r2 - ic * 9;
        float sc2 = bn2[oc] * rsqrtf(bn2[96 + oc] + EPSF);
        ws[WS_W2T + v] = c2w[oc * 288 + ic * 9 + tap] * sc2;
        float sc3 = bn3[oc] * rsqrtf(bn3[96 + oc] + EPSF);
        ws[WS_W3T + v] = c3w[oc * 288 + ic * 9 + tap] * sc3;
    }
    {
        float sc4 = bn4[0] * rsqrtf(bn4[3] + EPSF);
        for (int v = t; v < 288; v += 256) ws[WS_W4 + v] = c4w[v] * sc4;
        if (t == 0) ws[WS_B4] = (c4b[0] - bn4[2]) * sc4 + bn4[1];
    }
}

// ---------------------------------------------------------------------------
// Conv stack: 128 threads = 2 images (1 wave each). Lane = (row, oc-group-4).
// In-place conv on a single padded buffer [32ch][10rows][stride12].
// ---------------------------------------------------------------------------
__device__ __forceinline__ void conv_inplace(float* __restrict__ A,
                                             const float* __restrict__ Wg,
                                             const float* __restrict__ Bg,
                                             int r, int ocg)
{
    float acc[4][8];
    #pragma unroll
    for (int o = 0; o < 4; ++o)
        #pragma unroll
        for (int p = 0; p < 8; ++p) acc[o][p] = 0.f;

    const float* ap0 = A + r * 12;
    for (int ic = 0; ic < 32; ++ic) {
        const float* ap = ap0 + ic * 120;
        float R[3][12];
        #pragma unroll
        for (int dr = 0; dr < 3; ++dr) {
            *(float4*)&R[dr][0] = *(const float4*)(ap + dr * 12);
            *(float4*)&R[dr][4] = *(const float4*)(ap + dr * 12 + 4);
            *(float4*)&R[dr][8] = *(const float4*)(ap + dr * 12 + 8);
        }
        const float* wp = Wg + ic * 288 + ocg * 4;   // (ic*9+tap)*32 + oc
        #pragma unroll
        for (int dr = 0; dr < 3; ++dr)
            #pragma unroll
            for (int dc = 0; dc < 3; ++dc) {
                float4 w = *(const float4*)(wp + (dr * 3 + dc) * 32);
                #pragma unroll
                for (int p = 0; p < 8; ++p) {
                    float xv = R[dr][dc + p];
                    acc[0][p] += w.x * xv;
                    acc[1][p] += w.y * xv;
                    acc[2][p] += w.z * xv;
                    acc[3][p] += w.w * xv;
                }
            }
    }
    __syncthreads();                                 // all reads done before in-place writes
    float4 bb = *(const float4*)(Bg + ocg * 4);
    float bt[4] = {bb.x, bb.y, bb.z, bb.w};
    #pragma unroll
    for (int o = 0; o < 4; ++o)
        #pragma unroll
        for (int p = 0; p < 8; ++p)
            A[(ocg * 4 + o) * 120 + (r + 1) * 12 + (p + 1)] = gelu_f(acc[o][p] + bt[o]);
    __syncthreads();
}

__global__ void __launch_bounds__(128) feats_kernel(
    const float* __restrict__ sxs, const float* __restrict__ qxs,
    const float* __restrict__ lin_w, const float* __restrict__ ws,
    float* __restrict__ feats)
{
    __shared__ __align__(16) float sA[2][3840];     // padded conv buffer per image
    __shared__ __align__(16) float simg[2][1080];   // 30 rows, stride 36
    __shared__ __align__(16) float sh4[2][64];

    const int t   = threadIdx.x;
    const int wv  = t >> 6;
    const int l   = t & 63;
    const int r   = l & 7;
    const int ocg = l >> 3;
    const int n   = blockIdx.x * 2 + wv;

    // zero pads (and everything else)
    for (int i = t; i < 1920; i += 128) ((float4*)sA)[i]  = make_float4(0.f, 0.f, 0.f, 0.f);
    for (int i = t; i < 540;  i += 128) ((float4*)simg)[i] = make_float4(0.f, 0.f, 0.f, 0.f);
    __syncthreads();

    for (int i = t; i < 1568; i += 128) {
        int im = (i >= 784) ? 1 : 0;
        int j  = i - im * 784;
        int rr = j / 28, cc = j - rr * 28;
        int idx = blockIdx.x * 2 + im;
        const float* src = (idx < NSUP) ? (sxs + idx * 784) : (qxs + (idx - NSUP) * 784);
        simg[im][(rr + 1) * 36 + cc + 1] = src[j];
    }
    __syncthreads();

    float* A = sA[wv];
    const float* G = simg[wv];

    // Stage 1: conv1+bn1+pool+gelu as a 6x6 correlation; pool window start per out-row
    {
        const int so = (r * 7) >> 1;
        float acc[4][8];
        #pragma unroll
        for (int o = 0; o < 4; ++o)
            #pragma unroll
            for (int p = 0; p < 8; ++p) acc[o][p] = 0.f;
        const float* W1T = ws + WS_W1T;
        #pragma unroll
        for (int tt = 0; tt < 6; ++tt) {
            const float* rowp = G + (so + tt) * 36;
            float R[32];
            #pragma unroll
            for (int j = 0; j < 8; ++j) *(float4*)&R[j * 4] = *(const float4*)(rowp + j * 4);
            #pragma unroll
            for (int s = 0; s < 6; ++s) {
                float4 w = *(const float4*)(W1T + (tt * 6 + s) * 32 + ocg * 4);
                #pragma unroll
                for (int p = 0; p < 8; ++p) {
                    float xv = R[((p * 7) >> 1) + s];
                    acc[0][p] += w.x * xv;
                    acc[1][p] += w.y * xv;
                    acc[2][p] += w.z * xv;
                    acc[3][p] += w.w * xv;
                }
            }
        }
        float4 bb = *(const float4*)(ws + WS_B1 + ocg * 4);
        float bt[4] = {bb.x, bb.y, bb.z, bb.w};
        #pragma unroll
        for (int o = 0; o < 4; ++o)
            #pragma unroll
            for (int p = 0; p < 8; ++p)
                A[(ocg * 4 + o) * 120 + (r + 1) * 12 + (p + 1)] = gelu_f(acc[o][p] + bt[o]);
    }
    __syncthreads();

    conv_inplace(A, ws + WS_W2T, ws + WS_B2, r, ocg);   // conv2+bn2+gelu
    conv_inplace(A, ws + WS_W3T, ws + WS_B3, r, ocg);   // conv3+bn3+gelu

    // conv4 (32->1) + bn4 + gelu: lane = output pixel
    {
        const int rr = l >> 3, cc = l & 7;
        float a4 = 0.f;
        const float* W4 = ws + WS_W4;
        for (int ic = 0; ic < 32; ++ic) {
            const float* ap = A + ic * 120 + rr * 12 + cc;
            #pragma unroll
            for (int dr = 0; dr < 3; ++dr)
                #pragma unroll
                for (int dc = 0; dc < 3; ++dc)
                    a4 += W4[ic * 9 + dr * 3 + dc] * ap[dr * 12 + dc];
        }
        sh4[wv][l] = gelu_f(a4 + ws[WS_B4]);
    }
    __syncthreads();

    // Linear 64x64: lane = output feature
    {
        const float4* lw = (const float4*)(lin_w + l * 64);
        const float4* hp = (const float4*)sh4[wv];
        float acc = 0.f;
        #pragma unroll
        for (int j = 0; j < 16; ++j) {
            float4 w = lw[j], h = hp[j];
            acc += w.x * h.x + w.y * h.y + w.z * h.z + w.w * h.w;
        }
        feats[n * 64 + l] = acc;
    }
}

// ---------------------------------------------------------------------------
// Head: per batch element, fully in LDS; GEMM stages compute 4 outputs/lane
// with float4 reads on both operands. sW1T buffer is time-multiplexed:
// w1^T -> rq^T -> ro -> w1^T.
// ---------------------------------------------------------------------------
__device__ __forceinline__ float4 mm_unit(const float* __restrict__ xr,
                                          const float* __restrict__ wc)
{
    float4 a = {0.f, 0.f, 0.f, 0.f};
    #pragma unroll
    for (int j4 = 0; j4 < 16; ++j4) {
        float4 xv = *(const float4*)(xr + j4 * 4);
        float4 w0 = *(const float4*)(wc + (j4 * 4 + 0) * 64);
        float4 w1 = *(const float4*)(wc + (j4 * 4 + 1) * 64);
        float4 w2 = *(const float4*)(wc + (j4 * 4 + 2) * 64);
        float4 w3 = *(const float4*)(wc + (j4 * 4 + 3) * 64);
        a.x += xv.x * w0.x + xv.y * w1.x + xv.z * w2.x + xv.w * w3.x;
        a.y += xv.x * w0.y + xv.y * w1.y + xv.z * w2.y + xv.w * w3.y;
        a.z += xv.x * w0.z + xv.y * w1.z + xv.z * w2.z + xv.w * w3.z;
        a.w += xv.x * w0.w + xv.y * w1.w + xv.z * w2.w + xv.w * w3.w;
    }
    return a;
}

__global__ void __launch_bounds__(256) head_kernel(
    const float* __restrict__ w1, const float* __restrict__ w2,
    const float* __restrict__ emb, const float* __restrict__ tags,
    const float* __restrict__ rq, const float* __restrict__ rk,
    const float* __restrict__ rv, const float* __restrict__ ro,
    const float* __restrict__ lnw, const float* __restrict__ lnb,
    const int* __restrict__ sys, const int* __restrict__ qys,
    const float* __restrict__ feats, float* __restrict__ part)
{
    __shared__ __align__(16) float sW1T[4096];   // [j][e]; multiplexed
    __shared__ __align__(16) float sW2T[4096];   // [j][e]
    __shared__ __align__(16) float sRK[1024];
    __shared__ __align__(16) float sRV[1024];
    __shared__ __align__(16) float sX[1536];
    __shared__ __align__(16) float sP[1536];
    __shared__ __align__(16) float sQ[1536];
    __shared__ __align__(16) float sEM[128];
    __shared__ __align__(16) float sTG[320];
    __shared__ __align__(16) float sLW[64];
    __shared__ __align__(16) float sLB[64];
    __shared__ __align__(16) float s_xq[128];
    __shared__ __align__(16) float s_ah[128];
    __shared__ __align__(16) float s_yp[128];
    __shared__ float s_t1[12], s_t2[12], s_mu[24], s_rs[24], s_lg[4];

    const int t = threadIdx.x;
    const int b = blockIdx.x;

    // ---- stage constants ----
    for (int v = t; v < 1024; v += 256) {
        int e = v & 63, j4 = v >> 6;
        float4 g1 = *(const float4*)(w1 + e * 64 + j4 * 4);
        float4 g2 = *(const float4*)(w2 + e * 64 + j4 * 4);
        sW1T[(j4 * 4 + 0) * 64 + e] = g1.x; sW1T[(j4 * 4 + 1) * 64 + e] = g1.y;
        sW1T[(j4 * 4 + 2) * 64 + e] = g1.z; sW1T[(j4 * 4 + 3) * 64 + e] = g1.w;
        sW2T[(j4 * 4 + 0) * 64 + e] = g2.x; sW2T[(j4 * 4 + 1) * 64 + e] = g2.y;
        sW2T[(j4 * 4 + 2) * 64 + e] = g2.z; sW2T[(j4 * 4 + 3) * 64 + e] = g2.w;
    }
    for (int v = t; v < 1024; v += 256) { sRK[v] = rk[v]; sRV[v] = rv[v]; }
    for (int v = t; v < 320; v += 256) sTG[v] = tags[v];
    if (t < 128) sEM[t] = emb[t];
    if (t < 64) { sLW[t] = lnw[t]; sLB[t] = lnb[t]; }
    __syncthreads();

    // ---- tokens: sx + emb[sys] + tags[0..3] ----
    for (int idx = t; idx < 1536; idx += 256) {
        int k = idx >> 6, e = idx & 63;
        int s = k >> 2, tg = k & 3;
        int cls = sys[b * 6 + s];
        sX[idx] = feats[(b * 6 + s) * 64 + e] + sEM[cls * 64 + e] + sTG[tg * 64 + e];
    }
    __syncthreads();

    // ---- ah = gelu(X @ w1^T) -> sP ----
    for (int u = t; u < 384; u += 256) {
        int k = u >> 4, eg = u & 15;
        float4 a = mm_unit(sX + k * 64, sW1T + eg * 4);
        a.x = gelu_f(a.x); a.y = gelu_f(a.y); a.z = gelu_f(a.z); a.w = gelu_f(a.w);
        *(float4*)(sP + k * 64 + eg * 4) = a;
    }
    __syncthreads();

    // ---- q = ah @ w2^T -> sQ ; concurrently restage sW1T <- rq^T ----
    for (int u = t; u < 384; u += 256) {
        int k = u >> 4, eg = u & 15;
        *(float4*)(sQ + k * 64 + eg * 4) = mm_unit(sP + k * 64, sW2T + eg * 4);
    }
    __syncthreads();
    for (int v = t; v < 1024; v += 256) {
        int e = v & 63, j4 = v >> 6;          // e = nh
        float4 g = *(const float4*)(rq + e * 64 + j4 * 4);
        sW1T[(j4 * 4 + 0) * 64 + e] = g.x; sW1T[(j4 * 4 + 1) * 64 + e] = g.y;
        sW1T[(j4 * 4 + 2) * 64 + e] = g.z; sW1T[(j4 * 4 + 3) * 64 + e] = g.w;
    }
    __syncthreads();

    // ---- qh[k][nh] = q . rq[nh] -> sP ----
    for (int u = t; u < 384; u += 256) {
        int k = u >> 4, eg = u & 15;
        *(float4*)(sP + k * 64 + eg * 4) = mm_unit(sQ + k * 64, sW1T + eg * 4);
    }
    __syncthreads();

    // ---- attention over 16 slots -> lor in sQ; lanes >=128 copy ro -> sW1T ----
    if (t < 96) {
        int k = t >> 2, nn = t & 3;
        const float* qp = sP + k * 64 + nn * 16;
        float4 q0 = *(const float4*)(qp + 0), q1 = *(const float4*)(qp + 4);
        float4 q2 = *(const float4*)(qp + 8), q3 = *(const float4*)(qp + 12);
        float sc[16]; float mx = -1e30f;
        #pragma unroll
        for (int rr = 0; rr < 16; ++rr) {
            const float* kp = sRK + rr * 64 + nn * 16;
            float4 k0 = *(const float4*)(kp + 0), k1 = *(const float4*)(kp + 4);
            float4 k2 = *(const float4*)(kp + 8), k3 = *(const float4*)(kp + 12);
            float d = q0.x*k0.x + q0.y*k0.y + q0.z*k0.z + q0.w*k0.w
                    + q1.x*k1.x + q1.y*k1.y + q1.z*k1.z + q1.w*k1.w
                    + q2.x*k2.x + q2.y*k2.y + q2.z*k2.z + q2.w*k2.w
                    + q3.x*k3.x + q3.y*k3.y + q3.z*k3.z + q3.w*k3.w;
            d *= 0.25f;
            sc[rr] = d; mx = fmaxf(mx, d);
        }
        float sum = 0.f;
        #pragma unroll
        for (int rr = 0; rr < 16; ++rr) { sc[rr] = expf(sc[rr] - mx); sum += sc[rr]; }
        float inv = 1.0f / sum;
        float4 o0 = {0,0,0,0}, o1 = {0,0,0,0}, o2 = {0,0,0,0}, o3 = {0,0,0,0};
        #pragma unroll
        for (int rr = 0; rr < 16; ++rr) {
            const float* vp = sRV + rr * 64 + nn * 16;
            float p = sc[rr];
            float4 v0 = *(const float4*)(vp + 0), v1 = *(const float4*)(vp + 4);
            float4 v2 = *(const float4*)(vp + 8), v3 = *(const float4*)(vp + 12);
            o0.x += p*v0.x; o0.y += p*v0.y; o0.z += p*v0.z; o0.w += p*v0.w;
            o1.x += p*v1.x; o1.y += p*v1.y; o1.z += p*v1.z; o1.w += p*v1.w;
            o2.x += p*v2.x; o2.y += p*v2.y; o2.z += p*v2.z; o2.w += p*v2.w;
            o3.x += p*v3.x; o3.y += p*v3.y; o3.z += p*v3.z; o3.w += p*v3.w;
        }
        float* op = sQ + k * 64 + nn * 16;
        o0.x*=inv; o0.y*=inv; o0.z*=inv; o0.w*=inv;
        o1.x*=inv; o1.y*=inv; o1.z*=inv; o1.w*=inv;
        o2.x*=inv; o2.y*=inv; o2.z*=inv; o2.w*=inv;
        o3.x*=inv; o3.y*=inv; o3.z*=inv; o3.w*=inv;
        *(float4*)(op + 0) = o0; *(float4*)(op + 4) = o1;
        *(float4*)(op + 8) = o2; *(float4*)(op + 12) = o3;
    } else if (t >= 128) {
        for (int v = t - 128; v < 1024; v += 128)
            ((float4*)sW1T)[v] = ((const float4*)ro)[v];
    }
    __syncthreads();

    // ---- z = x + lor @ ro -> sP ----
    for (int u = t; u < 384; u += 256) {
        int k = u >> 4, eg = u & 15;
        float4 z = *(const float4*)(sX + k * 64 + eg * 4);
        float4 a = mm_unit(sQ + k * 64, sW1T + eg * 4);
        z.x += a.x; z.y += a.y; z.z += a.z; z.w += a.w;
        *(float4*)(sP + k * 64 + eg * 4) = z;
    }
    __syncthreads();

    // ---- LN stats (staggered); lanes >=64 restage sW1T <- w1^T ----
    if (t < 24) {
        const float4* zp = (const float4*)(sP + t * 64);
        float sx_ = 0.f;
        #pragma unroll
        for (int j = 0; j < 16; ++j) {
            float4 v = zp[(j + t) & 15];
            sx_ += v.x + v.y + v.z + v.w;
        }
        float mu = sx_ * (1.0f / 64.0f);
        float vv = 0.f;
        #pragma unroll
        for (int j = 0; j < 16; ++j) {
            float4 v = zp[(j + t) & 15];
            float d0 = v.x - mu, d1 = v.y - mu, d2 = v.z - mu, d3 = v.w - mu;
            vv += d0*d0 + d1*d1 + d2*d2 + d3*d3;
        }
        s_mu[t] = mu;
        s_rs[t] = 1.0f / sqrtf(vv * (1.0f / 64.0f) + EPSF);
    } else if (t >= 64) {
        for (int v = t - 64; v < 1024; v += 192) {
            int e = v & 63, j4 = v >> 6;
            float4 g = *(const float4*)(w1 + e * 64 + j4 * 4);
            sW1T[(j4 * 4 + 0) * 64 + e] = g.x; sW1T[(j4 * 4 + 1) * 64 + e] = g.y;
            sW1T[(j4 * 4 + 2) * 64 + e] = g.z; sW1T[(j4 * 4 + 3) * 64 + e] = g.w;
        }
    }
    __syncthreads();

    // ---- normalize -> sP holds lors (24 x 64) ----
    for (int u = t; u < 384; u += 256) {
        int k = u >> 4, eg = u & 15;
        float4 z = *(const float4*)(sP + k * 64 + eg * 4);
        float4 lw = *(const float4*)(sLW + eg * 4);
        float4 lb = *(const float4*)(sLB + eg * 4);
        float mu = s_mu[k], rs = s_rs[k];
        z.x = (z.x - mu) * rs * lw.x + lb.x;
        z.y = (z.y - mu) * rs * lw.y + lb.y;
        z.z = (z.z - mu) * rs * lw.z + lb.z;
        z.w = (z.w - mu) * rs * lw.w + lb.w;
        *(float4*)(sP + k * 64 + eg * 4) = z;
    }
    __syncthreads();

    // ---- preds on 2 query tokens with rank-6 updated weights ----
    if (t < 128) {
        int q = t >> 6, e = t & 63;
        s_xq[t] = feats[(NSUP + b * 2 + q) * 64 + e] + sTG[4 * 64 + e];
    }
    __syncthreads();
    if (t < 12) {
        int q = t / 6, s = t - q * 6;
        const float4* rp = (const float4*)(sP + (s * 4 + 1) * 64);
        const float4* xp = (const float4*)(s_xq + q * 64);
        float d = 0.f;
        #pragma unroll
        for (int j = 0; j < 16; ++j) {
            float4 a = rp[j], x = xp[j];
            d += a.x*x.x + a.y*x.y + a.z*x.z + a.w*x.w;
        }
        s_t1[t] = d;
    }
    __syncthreads();
    if (t < 128) {
        int q = t >> 6, e = t & 63;
        float acc = 0.f;
        const float* xq = s_xq + q * 64;
        #pragma unroll
        for (int j4 = 0; j4 < 16; ++j4) {
            float4 xv = *(const float4*)(xq + j4 * 4);
            acc += sW1T[(j4*4+0)*64+e]*xv.x + sW1T[(j4*4+1)*64+e]*xv.y
                 + sW1T[(j4*4+2)*64+e]*xv.z + sW1T[(j4*4+3)*64+e]*xv.w;
        }
        #pragma unroll
        for (int s = 0; s < 6; ++s) acc += sP[(s * 4 + 0) * 64 + e] * s_t1[q * 6 + s];
        s_ah[t] = gelu_f(acc);
    }
    __syncthreads();
    if (t < 12) {
        int q = t / 6, s = t - q * 6;
        const float4* rp = (const float4*)(sP + (s * 4 + 3) * 64);
        const float4* xp = (const float4*)(s_ah + q * 64);
        float d = 0.f;
        #pragma unroll
        for (int j = 0; j < 16; ++j) {
            float4 a = rp[j], x = xp[j];
            d += a.x*x.x + a.y*x.y + a.z*x.z + a.w*x.w;
        }
        s_t2[t] = d;
    }
    __syncthreads();
    if (t < 128) {
        int q = t >> 6, e = t & 63;
        float acc = 0.f;
        const float* ah = s_ah + q * 64;
        #pragma unroll
        for (int j4 = 0; j4 < 16; ++j4) {
            float4 xv = *(const float4*)(ah + j4 * 4);
            acc += sW2T[(j4*4+0)*64+e]*xv.x + sW2T[(j4*4+1)*64+e]*xv.y
                 + sW2T[(j4*4+2)*64+e]*xv.z + sW2T[(j4*4+3)*64+e]*xv.w;
        }
        #pragma unroll
        for (int s = 0; s < 6; ++s) acc += sP[(s * 4 + 2) * 64 + e] * s_t2[q * 6 + s];
        s_yp[t] = acc;
    }
    __syncthreads();
    if (t < 4) {
        int q = t >> 1, ll = t & 1;
        const float4* ep = (const float4*)(sEM + ll * 64);
        const float4* yp = (const float4*)(s_yp + q * 64);
        float d = 0.f;
        #pragma unroll
        for (int j = 0; j < 16; ++j) {
            float4 a = ep[j], x = yp[j];
            d += a.x*x.x + a.y*x.y + a.z*x.z + a.w*x.w;
        }
        s_lg[t] = d;
    }
    __syncthreads();
    if (t == 0) {
        float lsum = 0.f, corr = 0.f;
        #pragma unroll
        for (int q = 0; q < 2; ++q) {
            float l0 = s_lg[q * 2], l1 = s_lg[q * 2 + 1];
            int lab = qys[b * 2 + q];
            float m = fmaxf(l0, l1);
            float lse = m + logf(expf(l0 - m) + expf(l1 - m));
            lsum += -((lab ? l1 : l0) - lse);
            int pred = (l1 > l0) ? 1 : 0;
            corr += (pred == lab) ? 1.0f : 0.0f;
        }
        part[b] = lsum;
        part[512 + b] = corr;
    }
}

__global__ void __launch_bounds__(256) finalize_kernel(const float* __restrict__ part,
                                                       float* __restrict__ out)
{
    __shared__ float sl[256], sc[256];
    const int t = threadIdx.x;
    sl[t] = part[t] + part[t + 256];
    sc[t] = part[512 + t] + part[768 + t];
    __syncthreads();
    for (int s = 128; s > 0; s >>= 1) {
        if (t < s) { sl[t] += sl[t + s]; sc[t] += sc[t + s]; }
        __syncthreads();
    }
    if (t == 0) {
        float loss = sl[0] * (1.0f / 1024.0f);
        out[0] = loss;
        out[1] = loss;
        out[2] = 0.0f;
        out[3] = sc[0];
        out[4] = 1024.0f;
    }
}

extern "C" void kernel_launch(void* const* d_in, const int* in_sizes, int n_in,
                              void* d_out, int out_size, void* d_ws, size_t ws_size,
                              hipStream_t stream)
{
    (void)in_sizes; (void)n_in; (void)out_size; (void)ws_size;
    const float* sxs  = (const float*)d_in[1];
    const float* qxs  = (const float*)d_in[2];
    const float* c1w  = (const float*)d_in[4];
    const float* c1b  = (const float*)d_in[5];
    const float* bn1  = (const float*)d_in[6];
    const float* c2w  = (const float*)d_in[7];
    const float* c2b  = (const float*)d_in[8];
    const float* bn2  = (const float*)d_in[9];
    const float* c3w  = (const float*)d_in[10];
    const float* c3b  = (const float*)d_in[11];
    const float* bn3  = (const float*)d_in[12];
    const float* c4w  = (const float*)d_in[13];
    const float* c4b  = (const float*)d_in[14];
    const float* bn4  = (const float*)d_in[15];
    const float* lin_w= (const float*)d_in[16];
    const float* emb  = (const float*)d_in[17];
    const float* w1   = (const float*)d_in[18];
    const float* w2   = (const float*)d_in[19];
    const float* tags = (const float*)d_in[20];
    const float* rq   = (const float*)d_in[21];
    const float* rk   = (const float*)d_in[22];
    const float* rv   = (const float*)d_in[23];
    const float* ro   = (const float*)d_in[24];
    const float* lnw  = (const float*)d_in[25];
    const float* lnb  = (const float*)d_in[26];
    const int*   sys  = (const int*)d_in[27];
    const int*   qys  = (const int*)d_in[28];

    float* ws  = (float*)d_ws;
    float* out = (float*)d_out;

    precompute_kernel<<<1, 256, 0, stream>>>(c1w, c1b, bn1, c2w, c2b, bn2,
                                             c3w, c3b, bn3, c4w, c4b, bn4, ws);
    feats_kernel<<<2048, 128, 0, stream>>>(sxs, qxs, lin_w, ws, ws + WS_FEATS);
    head_kernel<<<512, 256, 0, stream>>>(w1, w2, emb, tags, rq, rk, rv, ro,
                                         lnw, lnb, sys, qys,
                                         ws + WS_FEATS, ws + WS_PART);
    finalize_kernel<<<1, 256, 0, stream>>>(ws + WS_PART, out);
}

// Round 3
// 325.318 us; speedup vs baseline: 1.2372x; 1.2110x over previous
//
#include <hip/hip_runtime.h>
#include <math.h>

constexpr int NSUP = 3072;            // B*S images
constexpr float EPSF = 1e-5f;

// Workspace layout (float offsets)
constexpr int WS_W1T  = 0;            // [tap36][oc32] conv1(x)pool composite, bn-scaled
constexpr int WS_B1   = 1152;         // 32 (contiguous after W1T)
constexpr int WS_W2T  = 1184;         // [ic32][tap9][oc32]
constexpr int WS_B2   = 10400;        // 32
constexpr int WS_W3T  = 10432;        // [ic32][tap9][oc32]
constexpr int WS_B3   = 19648;        // 32
constexpr int WS_W4   = 19680;        // [ic32][tap9]
constexpr int WS_B4   = 19968;        // 1 (+3 pad)
constexpr int WS_PART = 19972;        // [512] loss partials, [512] correct partials
constexpr int WS_FEATS= 20996;        // 4096*64

__device__ __forceinline__ float gelu_f(float x) {
    return 0.5f * x * (1.0f + erff(x * 0.70710678118654752440f));
}

// ---------------------------------------------------------------------------
// Precompute: fold BN into conv weights, emit tap-major (oc-fastest) layouts.
// ---------------------------------------------------------------------------
__global__ void __launch_bounds__(256) precompute_kernel(
    const float* __restrict__ c1w, const float* __restrict__ c1b, const float* __restrict__ bn1,
    const float* __restrict__ c2w, const float* __restrict__ c2b, const float* __restrict__ bn2,
    const float* __restrict__ c3w, const float* __restrict__ c3b, const float* __restrict__ bn3,
    const float* __restrict__ c4w, const float* __restrict__ c4b, const float* __restrict__ bn4,
    float* __restrict__ ws)
{
    const int t = threadIdx.x;
    if (t < 32) {
        const int c = t;
        float sc1 = bn1[c] * rsqrtf(bn1[96 + c] + EPSF);
        ws[WS_B1 + c] = (c1b[c] - bn1[64 + c]) * sc1 + bn1[32 + c];
        float sc2 = bn2[c] * rsqrtf(bn2[96 + c] + EPSF);
        ws[WS_B2 + c] = (c2b[c] - bn2[64 + c]) * sc2 + bn2[32 + c];
        float sc3 = bn3[c] * rsqrtf(bn3[96 + c] + EPSF);
        ws[WS_B3 + c] = (c3b[c] - bn3[64 + c]) * sc3 + bn3[32 + c];
    }
    // conv1 (x) 28->8 avgpool composite 6x6, tap-major [tap][oc]
    for (int v = t; v < 1152; v += 256) {
        int oc = v & 31, tap = v >> 5;
        int tt = tap / 6, s = tap - tt * 6;
        float sum = 0.f;
        for (int di = 0; di < 3; ++di) {
            int a = tt - di; if (a < 0 || a > 3) continue;
            for (int dj = 0; dj < 3; ++dj) {
                int bb = s - dj; if (bb < 0 || bb > 3) continue;
                sum += c1w[oc * 9 + di * 3 + dj];
            }
        }
        float sc1 = bn1[oc] * rsqrtf(bn1[96 + oc] + EPSF);
        ws[WS_W1T + v] = sum * sc1 * (1.0f / 16.0f);
    }
    // conv2/conv3 weights: [ic][tap][oc] (ic-quarters are contiguous 2304-float spans)
    for (int v = t; v < 9216; v += 256) {
        int oc = v & 31; int r2 = v >> 5;
        int ic = r2 / 9; int tap = r2 - ic * 9;
        float sc2 = bn2[oc] * rsqrtf(bn2[96 + oc] + EPSF);
        ws[WS_W2T + v] = c2w[oc * 288 + ic * 9 + tap] * sc2;
        float sc3 = bn3[oc] * rsqrtf(bn3[96 + oc] + EPSF);
        ws[WS_W3T + v] = c3w[oc * 288 + ic * 9 + tap] * sc3;
    }
    {
        float sc4 = bn4[0] * rsqrtf(bn4[3] + EPSF);
        for (int v = t; v < 288; v += 256) ws[WS_W4 + v] = c4w[v] * sc4;
        if (t == 0) ws[WS_B4] = (c4b[0] - bn4[2]) * sc4 + bn4[1];
    }
}

// ---------------------------------------------------------------------------
// Conv stack: 128 threads = 2 images (1 wave each). Lane = (row, oc-group-4).
// Weights staged into LDS in ic-quarters (2304 floats); activations in-place
// on a padded LDS buffer [32ch][10rows][stride12].
// ---------------------------------------------------------------------------
__device__ __forceinline__ void conv_lds(float* __restrict__ A,
                                         float* __restrict__ wbuf,
                                         const float* __restrict__ Wg,   // global [ic32][tap9][oc32]
                                         const float* __restrict__ Bg,   // global [oc32]
                                         int t, int r, int ocg)
{
    float acc[4][8];
    #pragma unroll
    for (int o = 0; o < 4; ++o)
        #pragma unroll
        for (int p = 0; p < 8; ++p) acc[o][p] = 0.f;

    const float* ap0 = A + r * 12;
    for (int g = 0; g < 4; ++g) {
        __syncthreads();    // prior quarter's reads done / prior layer writes visible
        {
            const float4* src = (const float4*)(Wg + g * 2304);
            for (int i = t; i < 576; i += 128) ((float4*)wbuf)[i] = src[i];
            if (g == 0 && t < 8) ((float4*)(wbuf + 2304))[t] = ((const float4*)Bg)[t];
        }
        __syncthreads();
        for (int ic8 = 0; ic8 < 8; ++ic8) {
            const float* ap = ap0 + (g * 8 + ic8) * 120;
            float R[3][12];
            #pragma unroll
            for (int dr = 0; dr < 3; ++dr) {
                *(float4*)&R[dr][0] = *(const float4*)(ap + dr * 12);
                *(float4*)&R[dr][4] = *(const float4*)(ap + dr * 12 + 4);
                *(float4*)&R[dr][8] = *(const float4*)(ap + dr * 12 + 8);
            }
            const float* wp = wbuf + ic8 * 288 + ocg * 4;    // (ic8*9+tap)*32 + oc
            #pragma unroll
            for (int dr = 0; dr < 3; ++dr)
                #pragma unroll
                for (int dc = 0; dc < 3; ++dc) {
                    float4 w = *(const float4*)(wp + (dr * 3 + dc) * 32);
                    #pragma unroll
                    for (int p = 0; p < 8; ++p) {
                        float xv = R[dr][dc + p];
                        acc[0][p] += w.x * xv;
                        acc[1][p] += w.y * xv;
                        acc[2][p] += w.z * xv;
                        acc[3][p] += w.w * xv;
                    }
                }
        }
    }
    __syncthreads();                     // all waves' reads of A complete before in-place writes
    float4 bb = *(const float4*)(wbuf + 2304 + ocg * 4);
    float bt[4] = {bb.x, bb.y, bb.z, bb.w};
    #pragma unroll
    for (int o = 0; o < 4; ++o)
        #pragma unroll
        for (int p = 0; p < 8; ++p)
            A[(ocg * 4 + o) * 120 + (r + 1) * 12 + (p + 1)] = gelu_f(acc[o][p] + bt[o]);
}

__global__ void __launch_bounds__(128, 2) feats_kernel(
    const float* __restrict__ sxs, const float* __restrict__ qxs,
    const float* __restrict__ lin_w, const float* __restrict__ ws,
    float* __restrict__ feats)
{
    __shared__ __align__(16) float sA[2][3840];   // padded conv buffer per image
    __shared__ __align__(16) float wbuf[2336];    // staged weight quarter + bias

    const int t   = threadIdx.x;
    const int wv  = t >> 6;
    const int l   = t & 63;
    const int r   = l & 7;
    const int ocg = l >> 3;
    const int n   = blockIdx.x * 2 + wv;

    float* A = sA[wv];

    // zero sA (pads stay zero forever); stage W1T+B1 (1184 floats)
    for (int i = t; i < 1920; i += 128) ((float4*)sA)[i] = make_float4(0.f, 0.f, 0.f, 0.f);
    for (int i = t; i < 296; i += 128) ((float4*)wbuf)[i] = ((const float4*)(ws + WS_W1T))[i];
    __syncthreads();

    // Stage 1: conv1+bn1+pool+gelu as a 6x6 correlation; image rows read from global
    {
        const float* img = (n < NSUP) ? (sxs + (size_t)n * 784) : (qxs + (size_t)(n - NSUP) * 784);
        const int so = (r * 7) >> 1;              // pool window starts {0,3,7,10,14,17,21,24}
        float acc[4][8];
        #pragma unroll
        for (int o = 0; o < 4; ++o)
            #pragma unroll
            for (int p = 0; p < 8; ++p) acc[o][p] = 0.f;
        #pragma unroll
        for (int tt = 0; tt < 6; ++tt) {
            int rr = so + tt - 1;                 // raw image row
            if (rr >= 0 && rr < 28) {
                float Rb[32];
                Rb[0] = 0.f; Rb[29] = 0.f; Rb[30] = 0.f; Rb[31] = 0.f;
                const float4* rp = (const float4*)(img + rr * 28);
                #pragma unroll
                for (int j = 0; j < 7; ++j) *(float4*)&Rb[1 + 4 * j] = rp[j];
                #pragma unroll
                for (int s = 0; s < 6; ++s) {
                    float4 w = *(const float4*)(wbuf + (tt * 6 + s) * 32 + ocg * 4);
                    #pragma unroll
                    for (int p = 0; p < 8; ++p) {
                        float xv = Rb[((p * 7) >> 1) + s];
                        acc[0][p] += w.x * xv;
                        acc[1][p] += w.y * xv;
                        acc[2][p] += w.z * xv;
                        acc[3][p] += w.w * xv;
                    }
                }
            }
        }
        float4 bb = *(const float4*)(wbuf + 1152 + ocg * 4);
        float bt[4] = {bb.x, bb.y, bb.z, bb.w};
        #pragma unroll
        for (int o = 0; o < 4; ++o)
            #pragma unroll
            for (int p = 0; p < 8; ++p)
                A[(ocg * 4 + o) * 120 + (r + 1) * 12 + (p + 1)] = gelu_f(acc[o][p] + bt[o]);
    }
    // conv_lds opens with __syncthreads -> stage1 writes visible, wbuf reads done

    conv_lds(A, wbuf, ws + WS_W2T, ws + WS_B2, t, r, ocg);   // conv2+bn2+gelu
    conv_lds(A, wbuf, ws + WS_W3T, ws + WS_B3, t, r, ocg);   // conv3+bn3+gelu

    __syncthreads();   // conv3 writes visible for conv4 reads
    // conv4 (32->1) + bn4 + gelu: lane = output pixel; weights are wave-uniform s_loads
    {
        const int rr = l >> 3, cc = l & 7;
        float a4 = 0.f;
        const float* W4 = ws + WS_W4;
        for (int ic = 0; ic < 32; ++ic) {
            const float* ap = A + ic * 120 + rr * 12 + cc;
            #pragma unroll
            for (int dr = 0; dr < 3; ++dr)
                #pragma unroll
                for (int dc = 0; dc < 3; ++dc)
                    a4 += W4[ic * 9 + dr * 3 + dc] * ap[dr * 12 + dc];
        }
        wbuf[wv * 64 + l] = gelu_f(a4 + ws[WS_B4]);   // wbuf free: all weight reads done
    }
    __syncthreads();

    // Linear 64x64: lane = output feature; lin_w from L1/L2-hot global
    {
        const float4* lw = (const float4*)(lin_w + (size_t)l * 64);
        const float4* hp = (const float4*)(wbuf + wv * 64);
        float acc = 0.f;
        #pragma unroll
        for (int j = 0; j < 16; ++j) {
            float4 w = lw[j], h = hp[j];
            acc += w.x * h.x + w.y * h.y + w.z * h.z + w.w * h.w;
        }
        feats[n * 64 + l] = acc;
    }
}

// ---------------------------------------------------------------------------
// Head: per batch element, fully in LDS; GEMM stages compute 4 outputs/lane
// with float4 reads on both operands. sW1T buffer is time-multiplexed:
// w1^T -> rq^T -> ro -> w1^T.
// ---------------------------------------------------------------------------
__device__ __forceinline__ float4 mm_unit(const float* __restrict__ xr,
                                          const float* __restrict__ wc)
{
    float4 a = {0.f, 0.f, 0.f, 0.f};
    #pragma unroll
    for (int j4 = 0; j4 < 16; ++j4) {
        float4 xv = *(const float4*)(xr + j4 * 4);
        float4 w0 = *(const float4*)(wc + (j4 * 4 + 0) * 64);
        float4 w1 = *(const float4*)(wc + (j4 * 4 + 1) * 64);
        float4 w2 = *(const float4*)(wc + (j4 * 4 + 2) * 64);
        float4 w3 = *(const float4*)(wc + (j4 * 4 + 3) * 64);
        a.x += xv.x * w0.x + xv.y * w1.x + xv.z * w2.x + xv.w * w3.x;
        a.y += xv.x * w0.y + xv.y * w1.y + xv.z * w2.y + xv.w * w3.y;
        a.z += xv.x * w0.z + xv.y * w1.z + xv.z * w2.z + xv.w * w3.z;
        a.w += xv.x * w0.w + xv.y * w1.w + xv.z * w2.w + xv.w * w3.w;
    }
    return a;
}

__global__ void __launch_bounds__(256) head_kernel(
    const float* __restrict__ w1, const float* __restrict__ w2,
    const float* __restrict__ emb, const float* __restrict__ tags,
    const float* __restrict__ rq, const float* __restrict__ rk,
    const float* __restrict__ rv, const float* __restrict__ ro,
    const float* __restrict__ lnw, const float* __restrict__ lnb,
    const int* __restrict__ sys, const int* __restrict__ qys,
    const float* __restrict__ feats, float* __restrict__ part)
{
    __shared__ __align__(16) float sW1T[4096];   // [j][e]; multiplexed
    __shared__ __align__(16) float sW2T[4096];   // [j][e]
    __shared__ __align__(16) float sRK[1024];
    __shared__ __align__(16) float sRV[1024];
    __shared__ __align__(16) float sX[1536];
    __shared__ __align__(16) float sP[1536];
    __shared__ __align__(16) float sQ[1536];
    __shared__ __align__(16) float sEM[128];
    __shared__ __align__(16) float sTG[320];
    __shared__ __align__(16) float sLW[64];
    __shared__ __align__(16) float sLB[64];
    __shared__ __align__(16) float s_xq[128];
    __shared__ __align__(16) float s_ah[128];
    __shared__ __align__(16) float s_yp[128];
    __shared__ float s_t1[12], s_t2[12], s_mu[24], s_rs[24], s_lg[4];

    const int t = threadIdx.x;
    const int b = blockIdx.x;

    // ---- stage constants ----
    for (int v = t; v < 1024; v += 256) {
        int e = v & 63, j4 = v >> 6;
        float4 g1 = *(const float4*)(w1 + e * 64 + j4 * 4);
        float4 g2 = *(const float4*)(w2 + e * 64 + j4 * 4);
        sW1T[(j4 * 4 + 0) * 64 + e] = g1.x; sW1T[(j4 * 4 + 1) * 64 + e] = g1.y;
        sW1T[(j4 * 4 + 2) * 64 + e] = g1.z; sW1T[(j4 * 4 + 3) * 64 + e] = g1.w;
        sW2T[(j4 * 4 + 0) * 64 + e] = g2.x; sW2T[(j4 * 4 + 1) * 64 + e] = g2.y;
        sW2T[(j4 * 4 + 2) * 64 + e] = g2.z; sW2T[(j4 * 4 + 3) * 64 + e] = g2.w;
    }
    for (int v = t; v < 1024; v += 256) { sRK[v] = rk[v]; sRV[v] = rv[v]; }
    for (int v = t; v < 320; v += 256) sTG[v] = tags[v];
    if (t < 128) sEM[t] = emb[t];
    if (t < 64) { sLW[t] = lnw[t]; sLB[t] = lnb[t]; }
    __syncthreads();

    // ---- tokens: sx + emb[sys] + tags[0..3] ----
    for (int idx = t; idx < 1536; idx += 256) {
        int k = idx >> 6, e = idx & 63;
        int s = k >> 2, tg = k & 3;
        int cls = sys[b * 6 + s];
        sX[idx] = feats[(b * 6 + s) * 64 + e] + sEM[cls * 64 + e] + sTG[tg * 64 + e];
    }
    __syncthreads();

    // ---- ah = gelu(X @ w1^T) -> sP ----
    for (int u = t; u < 384; u += 256) {
        int k = u >> 4, eg = u & 15;
        float4 a = mm_unit(sX + k * 64, sW1T + eg * 4);
        a.x = gelu_f(a.x); a.y = gelu_f(a.y); a.z = gelu_f(a.z); a.w = gelu_f(a.w);
        *(float4*)(sP + k * 64 + eg * 4) = a;
    }
    __syncthreads();

    // ---- q = ah @ w2^T -> sQ ; then restage sW1T <- rq^T ----
    for (int u = t; u < 384; u += 256) {
        int k = u >> 4, eg = u & 15;
        *(float4*)(sQ + k * 64 + eg * 4) = mm_unit(sP + k * 64, sW2T + eg * 4);
    }
    __syncthreads();
    for (int v = t; v < 1024; v += 256) {
        int e = v & 63, j4 = v >> 6;          // e = nh
        float4 g = *(const float4*)(rq + e * 64 + j4 * 4);
        sW1T[(j4 * 4 + 0) * 64 + e] = g.x; sW1T[(j4 * 4 + 1) * 64 + e] = g.y;
        sW1T[(j4 * 4 + 2) * 64 + e] = g.z; sW1T[(j4 * 4 + 3) * 64 + e] = g.w;
    }
    __syncthreads();

    // ---- qh[k][nh] = q . rq[nh] -> sP ----
    for (int u = t; u < 384; u += 256) {
        int k = u >> 4, eg = u & 15;
        *(float4*)(sP + k * 64 + eg * 4) = mm_unit(sQ + k * 64, sW1T + eg * 4);
    }
    __syncthreads();

    // ---- attention over 16 slots -> lor in sQ; lanes >=128 copy ro -> sW1T ----
    if (t < 96) {
        int k = t >> 2, nn = t & 3;
        const float* qp = sP + k * 64 + nn * 16;
        float4 q0 = *(const float4*)(qp + 0), q1 = *(const float4*)(qp + 4);
        float4 q2 = *(const float4*)(qp + 8), q3 = *(const float4*)(qp + 12);
        float sc[16]; float mx = -1e30f;
        #pragma unroll
        for (int rr = 0; rr < 16; ++rr) {
            const float* kp = sRK + rr * 64 + nn * 16;
            float4 k0 = *(const float4*)(kp + 0), k1 = *(const float4*)(kp + 4);
            float4 k2 = *(const float4*)(kp + 8), k3 = *(const float4*)(kp + 12);
            float d = q0.x*k0.x + q0.y*k0.y + q0.z*k0.z + q0.w*k0.w
                    + q1.x*k1.x + q1.y*k1.y + q1.z*k1.z + q1.w*k1.w
                    + q2.x*k2.x + q2.y*k2.y + q2.z*k2.z + q2.w*k2.w
                    + q3.x*k3.x + q3.y*k3.y + q3.z*k3.z + q3.w*k3.w;
            d *= 0.25f;
            sc[rr] = d; mx = fmaxf(mx, d);
        }
        float sum = 0.f;
        #pragma unroll
        for (int rr = 0; rr < 16; ++rr) { sc[rr] = expf(sc[rr] - mx); sum += sc[rr]; }
        float inv = 1.0f / sum;
        float4 o0 = {0,0,0,0}, o1 = {0,0,0,0}, o2 = {0,0,0,0}, o3 = {0,0,0,0};
        #pragma unroll
        for (int rr = 0; rr < 16; ++rr) {
            const float* vp = sRV + rr * 64 + nn * 16;
            float p = sc[rr];
            float4 v0 = *(const float4*)(vp + 0), v1 = *(const float4*)(vp + 4);
            float4 v2 = *(const float4*)(vp + 8), v3 = *(const float4*)(vp + 12);
            o0.x += p*v0.x; o0.y += p*v0.y; o0.z += p*v0.z; o0.w += p*v0.w;
            o1.x += p*v1.x; o1.y += p*v1.y; o1.z += p*v1.z; o1.w += p*v1.w;
            o2.x += p*v2.x; o2.y += p*v2.y; o2.z += p*v2.z; o2.w += p*v2.w;
            o3.x += p*v3.x; o3.y += p*v3.y; o3.z += p*v3.z; o3.w += p*v3.w;
        }
        float* op = sQ + k * 64 + nn * 16;
        o0.x*=inv; o0.y*=inv; o0.z*=inv; o0.w*=inv;
        o1.x*=inv; o1.y*=inv; o1.z*=inv; o1.w*=inv;
        o2.x*=inv; o2.y*=inv; o2.z*=inv; o2.w*=inv;
        o3.x*=inv; o3.y*=inv; o3.z*=inv; o3.w*=inv;
        *(float4*)(op + 0) = o0; *(float4*)(op + 4) = o1;
        *(float4*)(op + 8) = o2; *(float4*)(op + 12) = o3;
    } else if (t >= 128) {
        for (int v = t - 128; v < 1024; v += 128)
            ((float4*)sW1T)[v] = ((const float4*)ro)[v];
    }
    __syncthreads();

    // ---- z = x + lor @ ro -> sP ----
    for (int u = t; u < 384; u += 256) {
        int k = u >> 4, eg = u & 15;
        float4 z = *(const float4*)(sX + k * 64 + eg * 4);
        float4 a = mm_unit(sQ + k * 64, sW1T + eg * 4);
        z.x += a.x; z.y += a.y; z.z += a.z; z.w += a.w;
        *(float4*)(sP + k * 64 + eg * 4) = z;
    }
    __syncthreads();

    // ---- LN stats (staggered); lanes >=64 restage sW1T <- w1^T ----
    if (t < 24) {
        const float4* zp = (const float4*)(sP + t * 64);
        float sx_ = 0.f;
        #pragma unroll
        for (int j = 0; j < 16; ++j) {
            float4 v = zp[(j + t) & 15];
            sx_ += v.x + v.y + v.z + v.w;
        }
        float mu = sx_ * (1.0f / 64.0f);
        float vv = 0.f;
        #pragma unroll
        for (int j = 0; j < 16; ++j) {
            float4 v = zp[(j + t) & 15];
            float d0 = v.x - mu, d1 = v.y - mu, d2 = v.z - mu, d3 = v.w - mu;
            vv += d0*d0 + d1*d1 + d2*d2 + d3*d3;
        }
        s_mu[t] = mu;
        s_rs[t] = 1.0f / sqrtf(vv * (1.0f / 64.0f) + EPSF);
    } else if (t >= 64) {
        for (int v = t - 64; v < 1024; v += 192) {
            int e = v & 63, j4 = v >> 6;
            float4 g = *(const float4*)(w1 + e * 64 + j4 * 4);
            sW1T[(j4 * 4 + 0) * 64 + e] = g.x; sW1T[(j4 * 4 + 1) * 64 + e] = g.y;
            sW1T[(j4 * 4 + 2) * 64 + e] = g.z; sW1T[(j4 * 4 + 3) * 64 + e] = g.w;
        }
    }
    __syncthreads();

    // ---- normalize -> sP holds lors (24 x 64) ----
    for (int u = t; u < 384; u += 256) {
        int k = u >> 4, eg = u & 15;
        float4 z = *(const float4*)(sP + k * 64 + eg * 4);
        float4 lw = *(const float4*)(sLW + eg * 4);
        float4 lb = *(const float4*)(sLB + eg * 4);
        float mu = s_mu[k], rs = s_rs[k];
        z.x = (z.x - mu) * rs * lw.x + lb.x;
        z.y = (z.y - mu) * rs * lw.y + lb.y;
        z.z = (z.z - mu) * rs * lw.z + lb.z;
        z.w = (z.w - mu) * rs * lw.w + lb.w;
        *(float4*)(sP + k * 64 + eg * 4) = z;
    }
    __syncthreads();

    // ---- preds on 2 query tokens with rank-6 updated weights ----
    if (t < 128) {
        int q = t >> 6, e = t & 63;
        s_xq[t] = feats[(NSUP + b * 2 + q) * 64 + e] + sTG[4 * 64 + e];
    }
    __syncthreads();
    if (t < 12) {
        int q = t / 6, s = t - q * 6;
        const float4* rp = (const float4*)(sP + (s * 4 + 1) * 64);
        const float4* xp = (const float4*)(s_xq + q * 64);
        float d = 0.f;
        #pragma unroll
        for (int j = 0; j < 16; ++j) {
            float4 a = rp[j], x = xp[j];
            d += a.x*x.x + a.y*x.y + a.z*x.z + a.w*x.w;
        }
        s_t1[t] = d;
    }
    __syncthreads();
    if (t < 128) {
        int q = t >> 6, e = t & 63;
        float acc = 0.f;
        const float* xq = s_xq + q * 64;
        #pragma unroll
        for (int j4 = 0; j4 < 16; ++j4) {
            float4 xv = *(const float4*)(xq + j4 * 4);
            acc += sW1T[(j4*4+0)*64+e]*xv.x + sW1T[(j4*4+1)*64+e]*xv.y
                 + sW1T[(j4*4+2)*64+e]*xv.z + sW1T[(j4*4+3)*64+e]*xv.w;
        }
        #pragma unroll
        for (int s = 0; s < 6; ++s) acc += sP[(s * 4 + 0) * 64 + e] * s_t1[q * 6 + s];
        s_ah[t] = gelu_f(acc);
    }
    __syncthreads();
    if (t < 12) {
        int q = t / 6, s = t - q * 6;
        const float4* rp = (const float4*)(sP + (s * 4 + 3) * 64);
        const float4* xp = (const float4*)(s_ah + q * 64);
        float d = 0.f;
        #pragma unroll
        for (int j = 0; j < 16; ++j) {
            float4 a = rp[j], x = xp[j];
            d += a.x*x.x + a.y*x.y + a.z*x.z + a.w*x.w;
        }
        s_t2[t] = d;
    }
    __syncthreads();
    if (t < 128) {
        int q = t >> 6, e = t & 63;
        float acc = 0.f;
        const float* ah = s_ah + q * 64;
        #pragma unroll
        for (int j4 = 0; j4 < 16; ++j4) {
            float4 xv = *(const float4*)(ah + j4 * 4);
            acc += sW2T[(j4*4+0)*64+e]*xv.x + sW2T[(j4*4+1)*64+e]*xv.y
                 + sW2T[(j4*4+2)*64+e]*xv.z + sW2T[(j4*4+3)*64+e]*xv.w;
        }
        #pragma unroll
        for (int s = 0; s < 6; ++s) acc += sP[(s * 4 + 2) * 64 + e] * s_t2[q * 6 + s];
        s_yp[t] = acc;
    }
    __syncthreads();
    if (t < 4) {
        int q = t >> 1, ll = t & 1;
        const float4* ep = (const float4*)(sEM + ll * 64);
        const float4* yp = (const float4*)(s_yp + q * 64);
        float d = 0.f;
        #pragma unroll
        for (int j = 0; j < 16; ++j) {
            float4 a = ep[j], x = yp[j];
            d += a.x*x.x + a.y*x.y + a.z*x.z + a.w*x.w;
        }
        s_lg[t] = d;
    }
    __syncthreads();
    if (t == 0) {
        float lsum = 0.f, corr = 0.f;
        #pragma unroll
        for (int q = 0; q < 2; ++q) {
            float l0 = s_lg[q * 2], l1 = s_lg[q * 2 + 1];
            int lab = qys[b * 2 + q];
            float m = fmaxf(l0, l1);
            float lse = m + logf(expf(l0 - m) + expf(l1 - m));
            lsum += -((lab ? l1 : l0) - lse);
            int pred = (l1 > l0) ? 1 : 0;
            corr += (pred == lab) ? 1.0f : 0.0f;
        }
        part[b] = lsum;
        part[512 + b] = corr;
    }
}

__global__ void __launch_bounds__(256) finalize_kernel(const float* __restrict__ part,
                                                       float* __restrict__ out)
{
    __shared__ float sl[256], sc[256];
    const int t = threadIdx.x;
    sl[t] = part[t] + part[t + 256];
    sc[t] = part[512 + t] + part[768 + t];
    __syncthreads();
    for (int s = 128; s > 0; s >>= 1) {
        if (t < s) { sl[t] += sl[t + s]; sc[t] += sc[t + s]; }
        __syncthreads();
    }
    if (t == 0) {
        float loss = sl[0] * (1.0f / 1024.0f);
        out[0] = loss;
        out[1] = loss;
        out[2] = 0.0f;
        out[3] = sc[0];
        out[4] = 1024.0f;
    }
}

extern "C" void kernel_launch(void* const* d_in, const int* in_sizes, int n_in,
                              void* d_out, int out_size, void* d_ws, size_t ws_size,
                              hipStream_t stream)
{
    (void)in_sizes; (void)n_in; (void)out_size; (void)ws_size;
    const float* sxs  = (const float*)d_in[1];
    const float* qxs  = (const float*)d_in[2];
    const float* c1w  = (const float*)d_in[4];
    const float* c1b  = (const float*)d_in[5];
    const float* bn1  = (const float*)d_in[6];
    const float* c2w  = (const float*)d_in[7];
    const float* c2b  = (const float*)d_in[8];
    const float* bn2  = (const float*)d_in[9];
    const float* c3w  = (const float*)d_in[10];
    const float* c3b  = (const float*)d_in[11];
    const float* bn3  = (const float*)d_in[12];
    const float* c4w  = (const float*)d_in[13];
    const float* c4b  = (const float*)d_in[14];
    const float* bn4  = (const float*)d_in[15];
    const float* lin_w= (const float*)d_in[16];
    const float* emb  = (const float*)d_in[17];
    const float* w1   = (const float*)d_in[18];
    const float* w2   = (const float*)d_in[19];
    const float* tags = (const float*)d_in[20];
    const float* rq   = (const float*)d_in[21];
    const float* rk   = (const float*)d_in[22];
    const float* rv   = (const float*)d_in[23];
    const float* ro   = (const float*)d_in[24];
    const float* lnw  = (const float*)d_in[25];
    const float* lnb  = (const float*)d_in[26];
    const int*   sys  = (const int*)d_in[27];
    const int*   qys  = (const int*)d_in[28];

    float* ws  = (float*)d_ws;
    float* out = (float*)d_out;

    precompute_kernel<<<1, 256, 0, stream>>>(c1w, c1b, bn1, c2w, c2b, bn2,
                                             c3w, c3b, bn3, c4w, c4b, bn4, ws);
    feats_kernel<<<2048, 128, 0, stream>>>(sxs, qxs, lin_w, ws, ws + WS_FEATS);
    head_kernel<<<512, 256, 0, stream>>>(w1, w2, emb, tags, rq, rk, rv, ro,
                                         lnw, lnb, sys, qys,
                                         ws + WS_FEATS, ws + WS_PART);
    finalize_kernel<<<1, 256, 0, stream>>>(ws + WS_PART, out);
}

// Round 4
// 263.317 us; speedup vs baseline: 1.5285x; 1.2355x over previous
//
#include <hip/hip_runtime.h>
#include <math.h>

constexpr int NSUP = 3072;            // B*S images
constexpr float EPSF = 1e-5f;

// Workspace layout (float offsets)
constexpr int WS_W1T  = 0;            // [tap36][oc32] conv1(x)pool composite fp32
constexpr int WS_B1   = 1152;         // 32 (staged together with W1T)
constexpr int WS_B23  = 1184;         // 64 (b2, b3)
constexpr int WS_B4   = 1248;         // 1 (+3 pad)
constexpr int WS_W4   = 1252;         // [tap9][ic32] fp32 -> ends 1540
constexpr int WS_W2B  = 1540;         // bf16 [tap9][oc32][ic40] = 11520 ushort = 5760 f32 slots
constexpr int WS_W3B  = 7300;         // same -> ends 13060
constexpr int WS_PART = 13060;        // [512] loss partials, [512] correct partials
constexpr int WS_FEATS= 14084;        // 4096*64 f32

using short8 = __attribute__((ext_vector_type(8))) short;
using f32x4  = __attribute__((ext_vector_type(4))) float;

__device__ __forceinline__ float gelu_f(float x) {
    return 0.5f * x * (1.0f + erff(x * 0.70710678118654752440f));
}
__device__ __forceinline__ unsigned short f2bf(float f) {
    unsigned u = __float_as_uint(f);
    return (unsigned short)((u + 0x7FFFu + ((u >> 16) & 1u)) >> 16);
}

// ---------------------------------------------------------------------------
// Precompute: fold BN into weights; emit bf16 padded MFMA layouts for conv2/3.
// ---------------------------------------------------------------------------
__global__ void __launch_bounds__(256) precompute_kernel(
    const float* __restrict__ c1w, const float* __restrict__ c1b, const float* __restrict__ bn1,
    const float* __restrict__ c2w, const float* __restrict__ c2b, const float* __restrict__ bn2,
    const float* __restrict__ c3w, const float* __restrict__ c3b, const float* __restrict__ bn3,
    const float* __restrict__ c4w, const float* __restrict__ c4b, const float* __restrict__ bn4,
    float* __restrict__ ws)
{
    const int gid = blockIdx.x * 256 + threadIdx.x;
    const int gsz = gridDim.x * 256;

    for (int v = gid; v < 1152; v += gsz) {          // conv1 (x) pool composite, [tap][oc]
        int oc = v & 31, tap = v >> 5;
        int tt = tap / 6, s = tap - tt * 6;
        float sum = 0.f;
        for (int di = 0; di < 3; ++di) {
            int a = tt - di; if (a < 0 || a > 3) continue;
            for (int dj = 0; dj < 3; ++dj) {
                int bb = s - dj; if (bb < 0 || bb > 3) continue;
                sum += c1w[oc * 9 + di * 3 + dj];
            }
        }
        float sc1 = bn1[oc] * rsqrtf(bn1[96 + oc] + EPSF);
        ws[WS_W1T + v] = sum * sc1 * (1.0f / 16.0f);
    }
    for (int c = gid; c < 32; c += gsz) {
        float sc1 = bn1[c] * rsqrtf(bn1[96 + c] + EPSF);
        ws[WS_B1 + c] = (c1b[c] - bn1[64 + c]) * sc1 + bn1[32 + c];
        float sc2 = bn2[c] * rsqrtf(bn2[96 + c] + EPSF);
        ws[WS_B23 + c] = (c2b[c] - bn2[64 + c]) * sc2 + bn2[32 + c];
        float sc3 = bn3[c] * rsqrtf(bn3[96 + c] + EPSF);
        ws[WS_B23 + 32 + c] = (c3b[c] - bn3[64 + c]) * sc3 + bn3[32 + c];
    }
    {
        float sc4 = bn4[0] * rsqrtf(bn4[3] + EPSF);
        for (int v = gid; v < 288; v += gsz) {       // W4: [tap][ic]
            int tap = v >> 5, ic = v & 31;
            ws[WS_W4 + v] = c4w[ic * 9 + tap] * sc4;
        }
        if (gid == 0) ws[WS_B4] = (c4b[0] - bn4[2]) * sc4 + bn4[1];
    }
    // bf16 MFMA weights: [tap][oc][ic(pad 40)]
    unsigned short* w2b = (unsigned short*)(ws + WS_W2B);
    unsigned short* w3b = (unsigned short*)(ws + WS_W3B);
    for (int v = gid; v < 11520; v += gsz) {
        int tap = v / 1280; int r = v - tap * 1280;
        int oc = r / 40;    int ic = r - oc * 40;
        unsigned short v2 = 0, v3 = 0;
        if (ic < 32) {
            float sc2 = bn2[oc] * rsqrtf(bn2[96 + oc] + EPSF);
            float sc3 = bn3[oc] * rsqrtf(bn3[96 + oc] + EPSF);
            v2 = f2bf(c2w[oc * 288 + ic * 9 + tap] * sc2);
            v3 = f2bf(c3w[oc * 288 + ic * 9 + tap] * sc3);
        }
        w2b[v] = v2; w3b[v] = v3;
    }
}

// ---------------------------------------------------------------------------
// MFMA 3x3 conv: in-place on padded bf16 act buffer [10 rows][10 cols][40 ch].
// M=64 px, N=32 oc, K=32 ic per tap; 9 taps = 72 MFMAs. Wave-private.
// ---------------------------------------------------------------------------
__device__ __forceinline__ void conv_mfma(unsigned short* __restrict__ act,
                                          const unsigned short* __restrict__ wb,
                                          const float* __restrict__ bias, int lane)
{
    const int col  = lane & 15;
    const int quad = lane >> 4;
    f32x4 acc[4][2];
    #pragma unroll
    for (int mt = 0; mt < 4; ++mt)
        #pragma unroll
        for (int nt = 0; nt < 2; ++nt)
            acc[mt][nt] = (f32x4){0.f, 0.f, 0.f, 0.f};

    // A base per M-tile: px = mt*16 + col
    const unsigned short* abase[4];
    #pragma unroll
    for (int mt = 0; mt < 4; ++mt) {
        int px = mt * 16 + col;
        abase[mt] = act + ((px >> 3) * 10 + (px & 7)) * 40 + quad * 8;
    }
    const unsigned short* bbase = wb + col * 40 + quad * 8;

    #pragma unroll
    for (int dr = 0; dr < 3; ++dr)
        #pragma unroll
        for (int dc = 0; dc < 3; ++dc) {
            const int tap = dr * 3 + dc;
            short8 b0 = *(const short8*)(bbase + tap * 1280);
            short8 b1 = *(const short8*)(bbase + tap * 1280 + 640);
            #pragma unroll
            for (int mt = 0; mt < 4; ++mt) {
                short8 a = *(const short8*)(abase[mt] + (dr * 10 + dc) * 40);
                acc[mt][0] = __builtin_amdgcn_mfma_f32_16x16x32_bf16(a, b0, acc[mt][0], 0, 0, 0);
                acc[mt][1] = __builtin_amdgcn_mfma_f32_16x16x32_bf16(a, b1, acc[mt][1], 0, 0, 0);
            }
        }

    float bi0 = bias[col], bi1 = bias[col + 16];
    #pragma unroll
    for (int mt = 0; mt < 4; ++mt)
        #pragma unroll
        for (int reg = 0; reg < 4; ++reg) {
            int px = mt * 16 + quad * 4 + reg;
            unsigned short* dst = act + (((px >> 3) + 1) * 10 + (px & 7) + 1) * 40 + col;
            dst[0]  = f2bf(gelu_f(acc[mt][0][reg] + bi0));
            dst[16] = f2bf(gelu_f(acc[mt][1][reg] + bi1));
        }
}

__global__ void __launch_bounds__(256, 2) feats_kernel(
    const float* __restrict__ sxs, const float* __restrict__ qxs,
    const float* __restrict__ lin_w, const float* __restrict__ ws,
    float* __restrict__ feats)
{
    __shared__ __align__(16) float sW1[1184];
    __shared__ float sB23[64];
    __shared__ __align__(16) unsigned short sWB[11520];     // one conv layer's weights
    __shared__ __align__(16) unsigned short sAct[4][4000];  // [10][10][40] bf16 per image
    __shared__ float sh4[4][64];

    const int t    = threadIdx.x;
    const int wv   = t >> 6;
    const int lane = t & 63;
    const int n    = blockIdx.x * 4 + wv;

    // zero act buffers (pads must be 0); stage sW1+B1, biases, W2
    for (int i = t; i < 2000; i += 256) ((float4*)sAct)[i] = make_float4(0.f, 0.f, 0.f, 0.f);
    for (int i = t; i < 296;  i += 256) ((float4*)sW1)[i]  = ((const float4*)(ws + WS_W1T))[i];
    if (t < 64) sB23[t] = ws[WS_B23 + t];
    for (int i = t; i < 1440; i += 256) ((float4*)sWB)[i] = ((const float4*)(ws + WS_W2B))[i];
    __syncthreads();

    unsigned short* A = sAct[wv];

    // ---- Stage 1: conv1+bn1+pool(28->8)+gelu as 6x6 correlation, fp32 ----
    {
        const float* img = (n < NSUP) ? (sxs + (size_t)n * 784) : (qxs + (size_t)(n - NSUP) * 784);
        const int r = lane & 7, ocg = lane >> 3;
        const int so = (r * 7) >> 1;
        float acc[4][8];
        #pragma unroll
        for (int o = 0; o < 4; ++o)
            #pragma unroll
            for (int p = 0; p < 8; ++p) acc[o][p] = 0.f;
        #pragma unroll
        for (int tt = 0; tt < 6; ++tt) {
            int rr = so + tt - 1;
            if (rr >= 0 && rr < 28) {
                float Rb[32];
                Rb[0] = 0.f; Rb[29] = 0.f; Rb[30] = 0.f; Rb[31] = 0.f;
                const float4* rp = (const float4*)(img + rr * 28);
                #pragma unroll
                for (int j = 0; j < 7; ++j) *(float4*)&Rb[1 + 4 * j] = rp[j];
                #pragma unroll
                for (int s = 0; s < 6; ++s) {
                    float4 w = *(const float4*)(sW1 + (tt * 6 + s) * 32 + ocg * 4);
                    #pragma unroll
                    for (int p = 0; p < 8; ++p) {
                        float xv = Rb[((p * 7) >> 1) + s];
                        acc[0][p] += w.x * xv; acc[1][p] += w.y * xv;
                        acc[2][p] += w.z * xv; acc[3][p] += w.w * xv;
                    }
                }
            }
        }
        float4 bb = *(const float4*)(sW1 + 1152 + ocg * 4);
        float bt[4] = {bb.x, bb.y, bb.z, bb.w};
        #pragma unroll
        for (int c = 0; c < 8; ++c) {
            unsigned u0 = (unsigned)f2bf(gelu_f(acc[0][c] + bt[0]))
                        | ((unsigned)f2bf(gelu_f(acc[1][c] + bt[1])) << 16);
            unsigned u1 = (unsigned)f2bf(gelu_f(acc[2][c] + bt[2]))
                        | ((unsigned)f2bf(gelu_f(acc[3][c] + bt[3])) << 16);
            uint2 uu = {u0, u1};
            *(uint2*)(A + ((r + 1) * 10 + (c + 1)) * 40 + ocg * 4) = uu;
        }
    }
    __syncthreads();

    conv_mfma(A, sWB, sB23, lane);          // conv2+bn2+gelu (in-place, wave-private)
    __syncthreads();                         // all waves done with W2
    for (int i = t; i < 1440; i += 256) ((float4*)sWB)[i] = ((const float4*)(ws + WS_W3B))[i];
    __syncthreads();
    conv_mfma(A, sWB, sB23 + 32, lane);     // conv3+bn3+gelu
    __syncthreads();

    // ---- conv4 (32->1) + bn4 + gelu: lane = output pixel ----
    {
        const int pr = lane >> 3, pc = lane & 7;
        float a4 = 0.f;
        const float* W4 = ws + WS_W4;
        #pragma unroll
        for (int dr = 0; dr < 3; ++dr)
            #pragma unroll
            for (int dc = 0; dc < 3; ++dc) {
                const int tap = dr * 3 + dc;
                const uint4* pp = (const uint4*)(A + ((pr + dr) * 10 + (pc + dc)) * 40);
                const float* w = W4 + tap * 32;
                #pragma unroll
                for (int g = 0; g < 4; ++g) {
                    uint4 u = pp[g];
                    a4 += __uint_as_float(u.x << 16)            * w[g * 8 + 0];
                    a4 += __uint_as_float(u.x & 0xffff0000u)    * w[g * 8 + 1];
                    a4 += __uint_as_float(u.y << 16)            * w[g * 8 + 2];
                    a4 += __uint_as_float(u.y & 0xffff0000u)    * w[g * 8 + 3];
                    a4 += __uint_as_float(u.z << 16)            * w[g * 8 + 4];
                    a4 += __uint_as_float(u.z & 0xffff0000u)    * w[g * 8 + 5];
                    a4 += __uint_as_float(u.w << 16)            * w[g * 8 + 6];
                    a4 += __uint_as_float(u.w & 0xffff0000u)    * w[g * 8 + 7];
                }
            }
        sh4[wv][lane] = gelu_f(a4 + ws[WS_B4]);
    }
    __syncthreads();

    // ---- Linear 64x64: lane = output feature ----
    {
        const float4* lw = (const float4*)(lin_w + (size_t)lane * 64);
        const float4* hp = (const float4*)sh4[wv];
        float acc = 0.f;
        #pragma unroll
        for (int j = 0; j < 16; ++j) {
            float4 w = lw[j], h = hp[j];
            acc += w.x * h.x + w.y * h.y + w.z * h.z + w.w * h.w;
        }
        feats[n * 64 + lane] = acc;
    }
}

// ---------------------------------------------------------------------------
// Head: 2 batch elements per block (256 blocks). Weights shared in LDS,
// token arrays doubled (48 tokens -> 768 GEMM units = exactly 3/thread).
// ---------------------------------------------------------------------------
__device__ __forceinline__ float4 mm_unit(const float* __restrict__ xr,
                                          const float* __restrict__ wc)
{
    float4 a = {0.f, 0.f, 0.f, 0.f};
    #pragma unroll
    for (int j4 = 0; j4 < 16; ++j4) {
        float4 xv = *(const float4*)(xr + j4 * 4);
        float4 w0 = *(const float4*)(wc + (j4 * 4 + 0) * 64);
        float4 w1 = *(const float4*)(wc + (j4 * 4 + 1) * 64);
        float4 w2 = *(const float4*)(wc + (j4 * 4 + 2) * 64);
        float4 w3 = *(const float4*)(wc + (j4 * 4 + 3) * 64);
        a.x += xv.x * w0.x + xv.y * w1.x + xv.z * w2.x + xv.w * w3.x;
        a.y += xv.x * w0.y + xv.y * w1.y + xv.z * w2.y + xv.w * w3.y;
        a.z += xv.x * w0.z + xv.y * w1.z + xv.z * w2.z + xv.w * w3.z;
        a.w += xv.x * w0.w + xv.y * w1.w + xv.z * w2.w + xv.w * w3.w;
    }
    return a;
}

__global__ void __launch_bounds__(256) head_kernel(
    const float* __restrict__ w1, const float* __restrict__ w2,
    const float* __restrict__ emb, const float* __restrict__ tags,
    const float* __restrict__ rq, const float* __restrict__ rk,
    const float* __restrict__ rv, const float* __restrict__ ro,
    const float* __restrict__ lnw, const float* __restrict__ lnb,
    const int* __restrict__ sys, const int* __restrict__ qys,
    const float* __restrict__ feats, float* __restrict__ part)
{
    __shared__ __align__(16) float sW1T[4096];   // [j][e]; multiplexed w1^T->rq^T->ro->w1^T
    __shared__ __align__(16) float sW2T[4096];
    __shared__ __align__(16) float sX[3072];     // 48 tokens
    __shared__ __align__(16) float sP[3072];
    __shared__ __align__(16) float sQ[3072];
    __shared__ __align__(16) float sEM[128];
    __shared__ __align__(16) float sTG[320];
    __shared__ __align__(16) float sLW[64];
    __shared__ __align__(16) float sLB[64];
    __shared__ __align__(16) float s_xq[256];
    __shared__ __align__(16) float s_ah[256];
    __shared__ __align__(16) float s_yp[256];
    __shared__ float s_t1[24], s_t2[24], s_mu[48], s_rs[48], s_lg[8];

    const int t  = threadIdx.x;
    const int b0 = blockIdx.x * 2;

    for (int v = t; v < 1024; v += 256) {
        int e = v & 63, j4 = v >> 6;
        float4 g1 = *(const float4*)(w1 + e * 64 + j4 * 4);
        float4 g2 = *(const float4*)(w2 + e * 64 + j4 * 4);
        sW1T[(j4 * 4 + 0) * 64 + e] = g1.x; sW1T[(j4 * 4 + 1) * 64 + e] = g1.y;
        sW1T[(j4 * 4 + 2) * 64 + e] = g1.z; sW1T[(j4 * 4 + 3) * 64 + e] = g1.w;
        sW2T[(j4 * 4 + 0) * 64 + e] = g2.x; sW2T[(j4 * 4 + 1) * 64 + e] = g2.y;
        sW2T[(j4 * 4 + 2) * 64 + e] = g2.z; sW2T[(j4 * 4 + 3) * 64 + e] = g2.w;
    }
    for (int v = t; v < 320; v += 256) sTG[v] = tags[v];
    if (t < 128) sEM[t] = emb[t];
    if (t < 64) { sLW[t] = lnw[t]; sLB[t] = lnb[t]; }
    __syncthreads();

    // tokens: sx + emb[sys] + tags[0..3], 48 of them
    for (int idx = t; idx < 3072; idx += 256) {
        int kk = idx >> 6, e = idx & 63;
        int sub = kk >= 24, k = kk - 24 * sub;
        int s = k >> 2, tg = k & 3;
        int b = b0 + sub;
        int cls = sys[b * 6 + s];
        sX[idx] = feats[(b * 6 + s) * 64 + e] + sEM[cls * 64 + e] + sTG[tg * 64 + e];
    }
    __syncthreads();

    // ah = gelu(X @ w1^T) -> sP
    for (int u = t; u < 768; u += 256) {
        int k = u >> 4, eg = u & 15;
        float4 a = mm_unit(sX + k * 64, sW1T + eg * 4);
        a.x = gelu_f(a.x); a.y = gelu_f(a.y); a.z = gelu_f(a.z); a.w = gelu_f(a.w);
        *(float4*)(sP + k * 64 + eg * 4) = a;
    }
    __syncthreads();

    // q = ah @ w2^T -> sQ ; then restage sW1T <- rq^T
    for (int u = t; u < 768; u += 256) {
        int k = u >> 4, eg = u & 15;
        *(float4*)(sQ + k * 64 + eg * 4) = mm_unit(sP + k * 64, sW2T + eg * 4);
    }
    __syncthreads();
    for (int v = t; v < 1024; v += 256) {
        int e = v & 63, j4 = v >> 6;
        float4 g = *(const float4*)(rq + e * 64 + j4 * 4);
        sW1T[(j4 * 4 + 0) * 64 + e] = g.x; sW1T[(j4 * 4 + 1) * 64 + e] = g.y;
        sW1T[(j4 * 4 + 2) * 64 + e] = g.z; sW1T[(j4 * 4 + 3) * 64 + e] = g.w;
    }
    __syncthreads();

    // qh -> sP
    for (int u = t; u < 768; u += 256) {
        int k = u >> 4, eg = u & 15;
        *(float4*)(sP + k * 64 + eg * 4) = mm_unit(sQ + k * 64, sW1T + eg * 4);
    }
    __syncthreads();

    // attention (in-place in sP); lanes >=192 stage ro -> sW1T
    if (t < 192) {
        int kk = t >> 2, nn = t & 3;
        float* qp = sP + kk * 64 + nn * 16;
        float4 q0 = *(const float4*)(qp + 0), q1 = *(const float4*)(qp + 4);
        float4 q2 = *(const float4*)(qp + 8), q3 = *(const float4*)(qp + 12);
        float sc[16]; float mx = -1e30f;
        #pragma unroll
        for (int rr = 0; rr < 16; ++rr) {
            const float* kp = rk + rr * 64 + nn * 16;
            float4 k0 = *(const float4*)(kp + 0), k1 = *(const float4*)(kp + 4);
            float4 k2 = *(const float4*)(kp + 8), k3 = *(const float4*)(kp + 12);
            float d = q0.x*k0.x + q0.y*k0.y + q0.z*k0.z + q0.w*k0.w
                    + q1.x*k1.x + q1.y*k1.y + q1.z*k1.z + q1.w*k1.w
                    + q2.x*k2.x + q2.y*k2.y + q2.z*k2.z + q2.w*k2.w
                    + q3.x*k3.x + q3.y*k3.y + q3.z*k3.z + q3.w*k3.w;
            d *= 0.25f;
            sc[rr] = d; mx = fmaxf(mx, d);
        }
        float sum = 0.f;
        #pragma unroll
        for (int rr = 0; rr < 16; ++rr) { sc[rr] = expf(sc[rr] - mx); sum += sc[rr]; }
        float inv = 1.0f / sum;
        float4 o0 = {0,0,0,0}, o1 = {0,0,0,0}, o2 = {0,0,0,0}, o3 = {0,0,0,0};
        #pragma unroll
        for (int rr = 0; rr < 16; ++rr) {
            const float* vp = rv + rr * 64 + nn * 16;
            float p = sc[rr];
            float4 v0 = *(const float4*)(vp + 0), v1 = *(const float4*)(vp + 4);
            float4 v2 = *(const float4*)(vp + 8), v3 = *(const float4*)(vp + 12);
            o0.x += p*v0.x; o0.y += p*v0.y; o0.z += p*v0.z; o0.w += p*v0.w;
            o1.x += p*v1.x; o1.y += p*v1.y; o1.z += p*v1.z; o1.w += p*v1.w;
            o2.x += p*v2.x; o2.y += p*v2.y; o2.z += p*v2.z; o2.w += p*v2.w;
            o3.x += p*v3.x; o3.y += p*v3.y; o3.z += p*v3.z; o3.w += p*v3.w;
        }
        o0.x*=inv; o0.y*=inv; o0.z*=inv; o0.w*=inv;
        o1.x*=inv; o1.y*=inv; o1.z*=inv; o1.w*=inv;
        o2.x*=inv; o2.y*=inv; o2.z*=inv; o2.w*=inv;
        o3.x*=inv; o3.y*=inv; o3.z*=inv; o3.w*=inv;
        *(float4*)(qp + 0) = o0; *(float4*)(qp + 4) = o1;
        *(float4*)(qp + 8) = o2; *(float4*)(qp + 12) = o3;
    } else {
        for (int v = t - 192; v < 1024; v += 64)
            ((float4*)sW1T)[v] = ((const float4*)ro)[v];
    }
    __syncthreads();

    // z = x + lor @ ro -> sQ
    for (int u = t; u < 768; u += 256) {
        int k = u >> 4, eg = u & 15;
        float4 z = *(const float4*)(sX + k * 64 + eg * 4);
        float4 a = mm_unit(sP + k * 64, sW1T + eg * 4);
        z.x += a.x; z.y += a.y; z.z += a.z; z.w += a.w;
        *(float4*)(sQ + k * 64 + eg * 4) = z;
    }
    __syncthreads();

    // LN stats on sQ; lanes >=64 restage sW1T <- w1^T
    if (t < 48) {
        const float4* zp = (const float4*)(sQ + t * 64);
        float sx_ = 0.f;
        #pragma unroll
        for (int j = 0; j < 16; ++j) {
            float4 v = zp[(j + t) & 15];
            sx_ += v.x + v.y + v.z + v.w;
        }
        float mu = sx_ * (1.0f / 64.0f);
        float vv = 0.f;
        #pragma unroll
        for (int j = 0; j < 16; ++j) {
            float4 v = zp[(j + t) & 15];
            float d0 = v.x - mu, d1 = v.y - mu, d2 = v.z - mu, d3 = v.w - mu;
            vv += d0*d0 + d1*d1 + d2*d2 + d3*d3;
        }
        s_mu[t] = mu;
        s_rs[t] = 1.0f / sqrtf(vv * (1.0f / 64.0f) + EPSF);
    } else if (t >= 64) {
        for (int v = t - 64; v < 1024; v += 192) {
            int e = v & 63, j4 = v >> 6;
            float4 g = *(const float4*)(w1 + e * 64 + j4 * 4);
            sW1T[(j4 * 4 + 0) * 64 + e] = g.x; sW1T[(j4 * 4 + 1) * 64 + e] = g.y;
            sW1T[(j4 * 4 + 2) * 64 + e] = g.z; sW1T[(j4 * 4 + 3) * 64 + e] = g.w;
        }
    }
    __syncthreads();

    // normalize -> sQ holds lors (48 x 64)
    for (int u = t; u < 768; u += 256) {
        int k = u >> 4, eg = u & 15;
        float4 z = *(const float4*)(sQ + k * 64 + eg * 4);
        float4 lw = *(const float4*)(sLW + eg * 4);
        float4 lb = *(const float4*)(sLB + eg * 4);
        float mu = s_mu[k], rs = s_rs[k];
        z.x = (z.x - mu) * rs * lw.x + lb.x;
        z.y = (z.y - mu) * rs * lw.y + lb.y;
        z.z = (z.z - mu) * rs * lw.z + lb.z;
        z.w = (z.w - mu) * rs * lw.w + lb.w;
        *(float4*)(sQ + k * 64 + eg * 4) = z;
    }
    __syncthreads();

    // ---- preds: 4 query tokens (2 per batch element) ----
    {
        int qt = t >> 6, e = t & 63;
        int b = b0 + (qt >> 1), q = qt & 1;
        s_xq[t] = feats[(NSUP + b * 2 + q) * 64 + e] + sTG[256 + e];
    }
    __syncthreads();
    if (t < 24) {
        int qt = t / 6, s = t - qt * 6;
        int sub = qt >> 1;
        const float4* rp = (const float4*)(sQ + (sub * 24 + s * 4 + 1) * 64);
        const float4* xp = (const float4*)(s_xq + qt * 64);
        float d = 0.f;
        #pragma unroll
        for (int j = 0; j < 16; ++j) {
            float4 a = rp[j], x = xp[j];
            d += a.x*x.x + a.y*x.y + a.z*x.z + a.w*x.w;
        }
        s_t1[t] = d;
    }
    __syncthreads();
    {
        int qt = t >> 6, e = t & 63, sub = qt >> 1;
        float acc = 0.f;
        const float* xq = s_xq + qt * 64;
        #pragma unroll
        for (int j4 = 0; j4 < 16; ++j4) {
            float4 xv = *(const float4*)(xq + j4 * 4);
            acc += sW1T[(j4*4+0)*64+e]*xv.x + sW1T[(j4*4+1)*64+e]*xv.y
                 + sW1T[(j4*4+2)*64+e]*xv.z + sW1T[(j4*4+3)*64+e]*xv.w;
        }
        #pragma unroll
        for (int s = 0; s < 6; ++s)
            acc += sQ[(sub * 24 + s * 4 + 0) * 64 + e] * s_t1[qt * 6 + s];
        s_ah[t] = gelu_f(acc);
    }
    __syncthreads();
    if (t < 24) {
        int qt = t / 6, s = t - qt * 6;
        int sub = qt >> 1;
        const float4* rp = (const float4*)(sQ + (sub * 24 + s * 4 + 3) * 64);
        const float4* xp = (const float4*)(s_ah + qt * 64);
        float d = 0.f;
        #pragma unroll
        for (int j = 0; j < 16; ++j) {
            float4 a = rp[j], x = xp[j];
            d += a.x*x.x + a.y*x.y + a.z*x.z + a.w*x.w;
        }
        s_t2[t] = d;
    }
    __syncthreads();
    {
        int qt = t >> 6, e = t & 63, sub = qt >> 1;
        float acc = 0.f;
        const float* ah = s_ah + qt * 64;
        #pragma unroll
        for (int j4 = 0; j4 < 16; ++j4) {
            float4 xv = *(const float4*)(ah + j4 * 4);
            acc += sW2T[(j4*4+0)*64+e]*xv.x + sW2T[(j4*4+1)*64+e]*xv.y
                 + sW2T[(j4*4+2)*64+e]*xv.z + sW2T[(j4*4+3)*64+e]*xv.w;
        }
        #pragma unroll
        for (int s = 0; s < 6; ++s)
            acc += sQ[(sub * 24 + s * 4 + 2) * 64 + e] * s_t2[qt * 6 + s];
        s_yp[t] = acc;
    }
    __syncthreads();
    if (t < 8) {
        int qt = t >> 1, ll = t & 1;
        const float4* ep = (const float4*)(sEM + ll * 64);
        const float4* yp = (const float4*)(s_yp + qt * 64);
        float d = 0.f;
        #pragma unroll
        for (int j = 0; j < 16; ++j) {
            float4 a = ep[j], x = yp[j];
            d += a.x*x.x + a.y*x.y + a.z*x.z + a.w*x.w;
        }
        s_lg[t] = d;
    }
    __syncthreads();
    if (t < 2) {
        int b = b0 + t;
        float lsum = 0.f, corr = 0.f;
        #pragma unroll
        for (int q = 0; q < 2; ++q) {
            float l0 = s_lg[(t * 2 + q) * 2], l1 = s_lg[(t * 2 + q) * 2 + 1];
            int lab = qys[b * 2 + q];
            float m = fmaxf(l0, l1);
            float lse = m + logf(expf(l0 - m) + expf(l1 - m));
            lsum += -((lab ? l1 : l0) - lse);
            int pred = (l1 > l0) ? 1 : 0;
            corr += (pred == lab) ? 1.0f : 0.0f;
        }
        part[b] = lsum;
        part[512 + b] = corr;
    }
}

__global__ void __launch_bounds__(256) finalize_kernel(const float* __restrict__ part,
                                                       float* __restrict__ out)
{
    __shared__ float sl[256], sc[256];
    const int t = threadIdx.x;
    sl[t] = part[t] + part[t + 256];
    sc[t] = part[512 + t] + part[768 + t];
    __syncthreads();
    for (int s = 128; s > 0; s >>= 1) {
        if (t < s) { sl[t] += sl[t + s]; sc[t] += sc[t + s]; }
        __syncthreads();
    }
    if (t == 0) {
        float loss = sl[0] * (1.0f / 1024.0f);
        out[0] = loss;
        out[1] = loss;
        out[2] = 0.0f;
        out[3] = sc[0];
        out[4] = 1024.0f;
    }
}

extern "C" void kernel_launch(void* const* d_in, const int* in_sizes, int n_in,
                              void* d_out, int out_size, void* d_ws, size_t ws_size,
                              hipStream_t stream)
{
    (void)in_sizes; (void)n_in; (void)out_size; (void)ws_size;
    const float* sxs  = (const float*)d_in[1];
    const float* qxs  = (const float*)d_in[2];
    const float* c1w  = (const float*)d_in[4];
    const float* c1b  = (const float*)d_in[5];
    const float* bn1  = (const float*)d_in[6];
    const float* c2w  = (const float*)d_in[7];
    const float* c2b  = (const float*)d_in[8];
    const float* bn2  = (const float*)d_in[9];
    const float* c3w  = (const float*)d_in[10];
    const float* c3b  = (const float*)d_in[11];
    const float* bn3  = (const float*)d_in[12];
    const float* c4w  = (const float*)d_in[13];
    const float* c4b  = (const float*)d_in[14];
    const float* bn4  = (const float*)d_in[15];
    const float* lin_w= (const float*)d_in[16];
    const float* emb  = (const float*)d_in[17];
    const float* w1   = (const float*)d_in[18];
    const float* w2   = (const float*)d_in[19];
    const float* tags = (const float*)d_in[20];
    const float* rq   = (const float*)d_in[21];
    const float* rk   = (const float*)d_in[22];
    const float* rv   = (const float*)d_in[23];
    const float* ro   = (const float*)d_in[24];
    const float* lnw  = (const float*)d_in[25];
    const float* lnb  = (const float*)d_in[26];
    const int*   sys  = (const int*)d_in[27];
    const int*   qys  = (const int*)d_in[28];

    float* ws  = (float*)d_ws;
    float* out = (float*)d_out;

    precompute_kernel<<<64, 256, 0, stream>>>(c1w, c1b, bn1, c2w, c2b, bn2,
                                              c3w, c3b, bn3, c4w, c4b, bn4, ws);
    feats_kernel<<<1024, 256, 0, stream>>>(sxs, qxs, lin_w, ws, ws + WS_FEATS);
    head_kernel<<<256, 256, 0, stream>>>(w1, w2, emb, tags, rq, rk, rv, ro,
                                         lnw, lnb, sys, qys,
                                         ws + WS_FEATS, ws + WS_PART);
    finalize_kernel<<<1, 256, 0, stream>>>(ws + WS_PART, out);
}

// Round 6
// 174.072 us; speedup vs baseline: 2.3121x; 1.5127x over previous
//
#include <hip/hip_runtime.h>
#include <math.h>

constexpr int NSUP = 3072;            // B*S images
constexpr float EPSF = 1e-5f;

// Workspace layout (float offsets)
constexpr int WS_W1B  = 0;            // bf16 [kt2][oc32][k32] conv1(x)pool composite -> 1024 f
constexpr int WS_B1   = 1024;         // fp32 32
constexpr int WS_W2B  = 1056;         // bf16 [tap9][oc32][ic32] = 9216 ush = 4608 f
constexpr int WS_W3B  = 5664;         // same
constexpr int WS_W4B  = 10272;        // bf16 [tap9][ic32] = 288 ush = 144 f
constexpr int WS_B4   = 10416;        // fp32 1 (+pad)
constexpr int WS_B2   = 10420;        // fp32 32
constexpr int WS_B3   = 10452;        // fp32 32
constexpr int WS_HW1  = 10484;        // bf16 [64][72] = 4608 ush = 2304 f
constexpr int WS_HW2  = 12788;
constexpr int WS_HRQ  = 15092;
constexpr int WS_HROT = 17396;        // ro^T
constexpr int WS_PART = 19700;        // [512] loss, [512] correct
constexpr int WS_FEATS= 20724;        // 4096*64 f32

using short8 = __attribute__((ext_vector_type(8))) short;
using f32x4  = __attribute__((ext_vector_type(4))) float;

__device__ __forceinline__ float gelu_f(float x) {
    return 0.5f * x * (1.0f + erff(x * 0.70710678118654752440f));
}
__device__ __forceinline__ unsigned short f2bf(float f) {
    unsigned u = __float_as_uint(f);
    return (unsigned short)((u + 0x7FFFu + ((u >> 16) & 1u)) >> 16);
}
__device__ __forceinline__ float bflo(unsigned u) { return __uint_as_float(u << 16); }
__device__ __forceinline__ float bfhi(unsigned u) { return __uint_as_float(u & 0xffff0000u); }

// ---------------------------------------------------------------------------
// Precompute: fold BN; emit bf16 MFMA layouts for all conv + head weights.
// ---------------------------------------------------------------------------
__global__ void __launch_bounds__(256) precompute_kernel(
    const float* __restrict__ c1w, const float* __restrict__ c1b, const float* __restrict__ bn1,
    const float* __restrict__ c2w, const float* __restrict__ c2b, const float* __restrict__ bn2,
    const float* __restrict__ c3w, const float* __restrict__ c3b, const float* __restrict__ bn3,
    const float* __restrict__ c4w, const float* __restrict__ c4b, const float* __restrict__ bn4,
    const float* __restrict__ w1, const float* __restrict__ w2,
    const float* __restrict__ rq, const float* __restrict__ ro,
    float* __restrict__ ws)
{
    const int gid = blockIdx.x * 256 + threadIdx.x;
    const int gsz = gridDim.x * 256;

    // conv1 composite B: [kt][oc][k] with k=tap (0..35), zero-padded
    unsigned short* w1b = (unsigned short*)(ws + WS_W1B);
    for (int v = gid; v < 2048; v += gsz) {
        int kt = v >> 10, rem = v & 1023, oc = rem >> 5, kk = rem & 31;
        int tap = kt * 32 + kk;
        unsigned short o = 0;
        if (tap < 36) {
            int tt = tap / 6, s = tap - tt * 6;
            float sum = 0.f;
            for (int di = 0; di < 3; ++di) {
                int a = tt - di; if (a < 0 || a > 3) continue;
                for (int dj = 0; dj < 3; ++dj) {
                    int bb = s - dj; if (bb < 0 || bb > 3) continue;
                    sum += c1w[oc * 9 + di * 3 + dj];
                }
            }
            float sc1 = bn1[oc] * rsqrtf(bn1[96 + oc] + EPSF);
            o = f2bf(sum * sc1 * (1.0f / 16.0f));
        }
        w1b[v] = o;
    }
    for (int c = gid; c < 32; c += gsz) {
        float sc1 = bn1[c] * rsqrtf(bn1[96 + c] + EPSF);
        ws[WS_B1 + c] = (c1b[c] - bn1[64 + c]) * sc1 + bn1[32 + c];
        float sc2 = bn2[c] * rsqrtf(bn2[96 + c] + EPSF);
        ws[WS_B2 + c] = (c2b[c] - bn2[64 + c]) * sc2 + bn2[32 + c];
        float sc3 = bn3[c] * rsqrtf(bn3[96 + c] + EPSF);
        ws[WS_B3 + c] = (c3b[c] - bn3[64 + c]) * sc3 + bn3[32 + c];
    }
    // conv2/3: [tap][oc][ic] bf16
    unsigned short* w2b = (unsigned short*)(ws + WS_W2B);
    unsigned short* w3b = (unsigned short*)(ws + WS_W3B);
    for (int v = gid; v < 9216; v += gsz) {
        int tap = v >> 10, oc = (v >> 5) & 31, ic = v & 31;
        float sc2 = bn2[oc] * rsqrtf(bn2[96 + oc] + EPSF);
        float sc3 = bn3[oc] * rsqrtf(bn3[96 + oc] + EPSF);
        w2b[v] = f2bf(c2w[oc * 288 + ic * 9 + tap] * sc2);
        w3b[v] = f2bf(c3w[oc * 288 + ic * 9 + tap] * sc3);
    }
    {
        unsigned short* w4b = (unsigned short*)(ws + WS_W4B);
        float sc4 = bn4[0] * rsqrtf(bn4[3] + EPSF);
        for (int v = gid; v < 288; v += gsz) {
            int tap = v >> 5, ic = v & 31;
            w4b[v] = f2bf(c4w[ic * 9 + tap] * sc4);
        }
        if (gid == 0) ws[WS_B4] = (c4b[0] - bn4[2]) * sc4 + bn4[1];
    }
    // head weights bf16 [64][72]
    unsigned short* hw1 = (unsigned short*)(ws + WS_HW1);
    unsigned short* hw2 = (unsigned short*)(ws + WS_HW2);
    unsigned short* hrq = (unsigned short*)(ws + WS_HRQ);
    unsigned short* hro = (unsigned short*)(ws + WS_HROT);
    for (int v = gid; v < 4608; v += gsz) {
        int e = v / 72, d = v - e * 72;
        unsigned short a = 0, b = 0, c = 0, r = 0;
        if (d < 64) {
            a = f2bf(w1[e * 64 + d]);
            b = f2bf(w2[e * 64 + d]);
            c = f2bf(rq[e * 64 + d]);
            r = f2bf(ro[d * 64 + e]);
        }
        hw1[v] = a; hw2[v] = b; hrq[v] = c; hro[v] = r;
    }
}

// ---------------------------------------------------------------------------
// feats: 512 threads = 8 waves = 8 images. Full-MFMA conv stack.
// Act buffer per image: [10 rows][10 cols][32 ch] bf16 (halo zeros).
// ---------------------------------------------------------------------------
__global__ void __launch_bounds__(512, 4) feats_kernel(
    const float* __restrict__ sxs, const float* __restrict__ qxs,
    const float* __restrict__ lin_w, const float* __restrict__ ws,
    float* __restrict__ feats)
{
    __shared__ __align__(16) unsigned short sAct[8][3200];
    __shared__ __align__(16) unsigned short sWB[9216];
    __shared__ __align__(16) float sh4[8][64];

    const int t    = threadIdx.x;
    const int wv   = t >> 6;
    const int lane = t & 63;
    const int col  = lane & 15;
    const int quad = lane >> 4;
    const int n    = blockIdx.x * 8 + wv;

    unsigned short* A = sAct[wv];

    {   // zero act buffers (25600 ush = 3200 uint4); stage W1B (2048 ush = 256 uint4)
        uint4 z = {0, 0, 0, 0};
        for (int i = t; i < 3200; i += 512) ((uint4*)sAct)[i] = z;
        if (t < 256) ((uint4*)sWB)[t] = ((const uint4*)(ws + WS_W1B))[t];
    }
    __syncthreads();

    // ---- Stage 1: conv1+bn1+pool+gelu as 64x32xK36 MFMA GEMM ----
    {
        const float* img = (n < NSUP) ? (sxs + (size_t)n * 784) : (qxs + (size_t)(n - NSUP) * 784);
        int ttj[8], ssj[8];
        #pragma unroll
        for (int j = 0; j < 8; ++j) {
            int k = quad * 8 + j;
            ttj[j] = k / 6; ssj[j] = k - ttj[j] * 6;
        }
        f32x4 acc[4][2];
        #pragma unroll
        for (int mt = 0; mt < 4; ++mt) { acc[mt][0] = (f32x4){0,0,0,0}; acc[mt][1] = (f32x4){0,0,0,0}; }

        short8 b00 = *(const short8*)(sWB + (0 * 32 + 0 * 16 + col) * 32 + quad * 8);
        short8 b01 = *(const short8*)(sWB + (0 * 32 + 1 * 16 + col) * 32 + quad * 8);
        short8 b10 = *(const short8*)(sWB + (1 * 32 + 0 * 16 + col) * 32 + quad * 8);
        short8 b11 = *(const short8*)(sWB + (1 * 32 + 1 * 16 + col) * 32 + quad * 8);

        #pragma unroll
        for (int mt = 0; mt < 4; ++mt) {
            int px = mt * 16 + col;
            int sr = (((px >> 3) * 7) >> 1) - 1;
            int sc = (((px & 7) * 7) >> 1) - 1;
            short8 a0;
            #pragma unroll
            for (int j = 0; j < 8; ++j) {
                int rr = sr + ttj[j], cc = sc + ssj[j];
                float v = ((unsigned)rr < 28u && (unsigned)cc < 28u) ? img[rr * 28 + cc] : 0.f;
                a0[j] = (short)f2bf(v);
            }
            acc[mt][0] = __builtin_amdgcn_mfma_f32_16x16x32_bf16(a0, b00, acc[mt][0], 0, 0, 0);
            acc[mt][1] = __builtin_amdgcn_mfma_f32_16x16x32_bf16(a0, b01, acc[mt][1], 0, 0, 0);
            short8 a1 = {0,0,0,0,0,0,0,0};
            if (quad == 0) {
                #pragma unroll
                for (int j = 0; j < 4; ++j) {          // k=32..35 -> tt=5, ss=2+j
                    int rr = sr + 5, cc = sc + 2 + j;
                    float v = ((unsigned)rr < 28u && (unsigned)cc < 28u) ? img[rr * 28 + cc] : 0.f;
                    a1[j] = (short)f2bf(v);
                }
            }
            acc[mt][0] = __builtin_amdgcn_mfma_f32_16x16x32_bf16(a1, b10, acc[mt][0], 0, 0, 0);
            acc[mt][1] = __builtin_amdgcn_mfma_f32_16x16x32_bf16(a1, b11, acc[mt][1], 0, 0, 0);
        }
        float bi0 = ws[WS_B1 + col], bi1 = ws[WS_B1 + 16 + col];
        #pragma unroll
        for (int mt = 0; mt < 4; ++mt)
            #pragma unroll
            for (int reg = 0; reg < 4; ++reg) {
                int px = mt * 16 + quad * 4 + reg;
                unsigned short* dst = A + (((px >> 3) + 1) * 10 + (px & 7) + 1) * 32;
                dst[col]      = f2bf(gelu_f(acc[mt][0][reg] + bi0));
                dst[col + 16] = f2bf(gelu_f(acc[mt][1][reg] + bi1));
            }
    }
    __syncthreads();
    for (int i = t; i < 1152; i += 512) ((uint4*)sWB)[i] = ((const uint4*)(ws + WS_W2B))[i];
    __syncthreads();

    // ---- conv2 / conv3: in-place MFMA (wave-private act buffer) ----
    #pragma unroll 1
    for (int layer = 0; layer < 2; ++layer) {
        f32x4 acc[4][2];
        #pragma unroll
        for (int mt = 0; mt < 4; ++mt) { acc[mt][0] = (f32x4){0,0,0,0}; acc[mt][1] = (f32x4){0,0,0,0}; }
        const unsigned short* abase[4];
        #pragma unroll
        for (int mt = 0; mt < 4; ++mt) {
            int px = mt * 16 + col;
            abase[mt] = A + ((px >> 3) * 10 + (px & 7)) * 32 + quad * 8;
        }
        #pragma unroll
        for (int dr = 0; dr < 3; ++dr)
            #pragma unroll
            for (int dc = 0; dc < 3; ++dc) {
                int tap = dr * 3 + dc;
                short8 b0 = *(const short8*)(sWB + (tap * 32 + col) * 32 + quad * 8);
                short8 b1 = *(const short8*)(sWB + (tap * 32 + 16 + col) * 32 + quad * 8);
                #pragma unroll
                for (int mt = 0; mt < 4; ++mt) {
                    short8 a = *(const short8*)(abase[mt] + (dr * 10 + dc) * 32);
                    acc[mt][0] = __builtin_amdgcn_mfma_f32_16x16x32_bf16(a, b0, acc[mt][0], 0, 0, 0);
                    acc[mt][1] = __builtin_amdgcn_mfma_f32_16x16x32_bf16(a, b1, acc[mt][1], 0, 0, 0);
                }
            }
        float bi0 = ws[(layer ? WS_B3 : WS_B2) + col];
        float bi1 = ws[(layer ? WS_B3 : WS_B2) + 16 + col];
        #pragma unroll
        for (int mt = 0; mt < 4; ++mt)
            #pragma unroll
            for (int reg = 0; reg < 4; ++reg) {
                int px = mt * 16 + quad * 4 + reg;
                unsigned short* dst = A + (((px >> 3) + 1) * 10 + (px & 7) + 1) * 32;
                dst[col]      = f2bf(gelu_f(acc[mt][0][reg] + bi0));
                dst[col + 16] = f2bf(gelu_f(acc[mt][1][reg] + bi1));
            }
        __syncthreads();
        if (layer == 0) {
            for (int i = t; i < 1152; i += 512) ((uint4*)sWB)[i] = ((const uint4*)(ws + WS_W3B))[i];
            __syncthreads();
        }
    }

    // ---- conv4 (32->1) via broadcast-B MFMA ----
    {
        f32x4 acc4[4];
        #pragma unroll
        for (int mt = 0; mt < 4; ++mt) acc4[mt] = (f32x4){0,0,0,0};
        const unsigned short* abase[4];
        #pragma unroll
        for (int mt = 0; mt < 4; ++mt) {
            int px = mt * 16 + col;
            abase[mt] = A + ((px >> 3) * 10 + (px & 7)) * 32 + quad * 8;
        }
        const unsigned short* w4g = (const unsigned short*)(ws + WS_W4B);
        #pragma unroll
        for (int dr = 0; dr < 3; ++dr)
            #pragma unroll
            for (int dc = 0; dc < 3; ++dc) {
                int tap = dr * 3 + dc;
                short8 b = *(const short8*)(w4g + tap * 32 + quad * 8);
                #pragma unroll
                for (int mt = 0; mt < 4; ++mt) {
                    short8 a = *(const short8*)(abase[mt] + (dr * 10 + dc) * 32);
                    acc4[mt] = __builtin_amdgcn_mfma_f32_16x16x32_bf16(a, b, acc4[mt], 0, 0, 0);
                }
            }
        if (col < 4) {
            f32x4 v = acc4[0];
            if (col == 1) v = acc4[1];
            else if (col == 2) v = acc4[2];
            else if (col == 3) v = acc4[3];
            float b4 = ws[WS_B4];
            #pragma unroll
            for (int reg = 0; reg < 4; ++reg)
                sh4[wv][col * 16 + quad * 4 + reg] = gelu_f(v[reg] + b4);
        }
    }
    __syncthreads();

    // ---- Linear 64x64 fp32 ----
    {
        const float4* lw = (const float4*)(lin_w + (size_t)lane * 64);
        const float4* hp = (const float4*)sh4[wv];
        float acc = 0.f;
        #pragma unroll
        for (int j = 0; j < 16; ++j) {
            float4 w = lw[j], h = hp[j];
            acc += w.x * h.x + w.y * h.y + w.z * h.z + w.w * h.w;
        }
        feats[n * 64 + lane] = acc;
    }
}

// ---------------------------------------------------------------------------
// head: 1 batch element per block, 256 threads, bf16 MFMA GEMMs.
// Buffers: bufA/bufB bf16 [32][72] (rows 24..31 zero); sXf fp32 residual.
// ---------------------------------------------------------------------------
__device__ __forceinline__ void head_gemm(const unsigned short* __restrict__ Ab,
                                          const unsigned short* __restrict__ Bw,
                                          int col, int quad, int wvid, f32x4 res[2])
{
    #pragma unroll
    for (int u = 0; u < 2; ++u) {
        int tau = wvid + u * 4;
        int mt = tau & 1, nt = tau >> 1;
        f32x4 acc = {0, 0, 0, 0};
        #pragma unroll
        for (int kt = 0; kt < 2; ++kt) {
            short8 a = *(const short8*)(Ab + (mt * 16 + col) * 72 + kt * 32 + quad * 8);
            short8 b = *(const short8*)(Bw + (nt * 16 + col) * 72 + kt * 32 + quad * 8);
            acc = __builtin_amdgcn_mfma_f32_16x16x32_bf16(a, b, acc, 0, 0, 0);
        }
        res[u] = acc;
    }
}

__global__ void __launch_bounds__(256, 2) head_kernel(
    const float* __restrict__ emb, const float* __restrict__ tags,
    const float* __restrict__ rk, const float* __restrict__ rv,
    const float* __restrict__ lnw, const float* __restrict__ lnb,
    const int* __restrict__ sys, const int* __restrict__ qys,
    const float* __restrict__ ws, const float* __restrict__ feats,
    float* __restrict__ part)
{
    __shared__ __align__(16) unsigned short sW1B[4608], sW2B[4608], sRQB[4608], sROT[4608];
    __shared__ __align__(16) unsigned short bufA[2304], bufB[2304];
    __shared__ __align__(16) float sXf[1536];
    __shared__ __align__(16) float s_xq[128], s_ah[128], s_yp[128];
    __shared__ float s_t1[12], s_t2[12], s_mu[24], s_rs[24], s_lg[4];

    const int t    = threadIdx.x;
    const int b    = blockIdx.x;
    const int wvid = t >> 6;
    const int col  = t & 15;
    const int quad = (t >> 4) & 3;

    for (int i = t; i < 576; i += 256) {      // 4608 ush = 576 uint4 each
        ((uint4*)sW1B)[i] = ((const uint4*)(ws + WS_HW1))[i];
        ((uint4*)sW2B)[i] = ((const uint4*)(ws + WS_HW2))[i];
        ((uint4*)sRQB)[i] = ((const uint4*)(ws + WS_HRQ))[i];
        ((uint4*)sROT)[i] = ((const uint4*)(ws + WS_HROT))[i];
    }
    if (t < 72) {   // zero pad rows 24..31 (576 ush = 72 uint4 each)
        uint4 z = {0, 0, 0, 0};
        ((uint4*)(bufA + 1728))[t] = z;
        ((uint4*)(bufB + 1728))[t] = z;
    }
    // tokens (fp32 + bf16)
    for (int idx = t; idx < 1536; idx += 256) {
        int k = idx >> 6, e = idx & 63;
        int s = k >> 2, tg = k & 3;
        int cls = sys[b * 6 + s];
        float v = feats[(b * 6 + s) * 64 + e] + emb[cls * 64 + e] + tags[tg * 64 + e];
        sXf[idx] = v;
        bufA[k * 72 + e] = f2bf(v);
    }
    __syncthreads();

    f32x4 r[2];
    // GEMM1: ah = gelu(X @ w1^T) -> bufB
    head_gemm(bufA, sW1B, col, quad, wvid, r);
    #pragma unroll
    for (int u = 0; u < 2; ++u) {
        int tau = wvid + u * 4, mt = tau & 1, nt = tau >> 1;
        #pragma unroll
        for (int reg = 0; reg < 4; ++reg) {
            int row = mt * 16 + quad * 4 + reg;
            if (row < 24) bufB[row * 72 + nt * 16 + col] = f2bf(gelu_f(r[u][reg]));
        }
    }
    __syncthreads();
    // GEMM2: q = ah @ w2^T -> bufA
    head_gemm(bufB, sW2B, col, quad, wvid, r);
    #pragma unroll
    for (int u = 0; u < 2; ++u) {
        int tau = wvid + u * 4, mt = tau & 1, nt = tau >> 1;
        #pragma unroll
        for (int reg = 0; reg < 4; ++reg) {
            int row = mt * 16 + quad * 4 + reg;
            if (row < 24) bufA[row * 72 + nt * 16 + col] = f2bf(r[u][reg]);
        }
    }
    __syncthreads();
    // GEMM3: qh = q @ rq^T -> bufB
    head_gemm(bufA, sRQB, col, quad, wvid, r);
    #pragma unroll
    for (int u = 0; u < 2; ++u) {
        int tau = wvid + u * 4, mt = tau & 1, nt = tau >> 1;
        #pragma unroll
        for (int reg = 0; reg < 4; ++reg) {
            int row = mt * 16 + quad * 4 + reg;
            if (row < 24) bufB[row * 72 + nt * 16 + col] = f2bf(r[u][reg]);
        }
    }
    __syncthreads();

    // attention over 16 slots per (k, head) -> lor bf16 in bufA
    if (t < 96) {
        int k = t >> 2, nn = t & 3;
        const unsigned short* qp = bufB + k * 72 + nn * 16;
        uint4 u0 = *(const uint4*)(qp);
        uint4 u1 = *(const uint4*)(qp + 8);
        float qv[16];
        qv[0]=bflo(u0.x); qv[1]=bfhi(u0.x); qv[2]=bflo(u0.y); qv[3]=bfhi(u0.y);
        qv[4]=bflo(u0.z); qv[5]=bfhi(u0.z); qv[6]=bflo(u0.w); qv[7]=bfhi(u0.w);
        qv[8]=bflo(u1.x); qv[9]=bfhi(u1.x); qv[10]=bflo(u1.y); qv[11]=bfhi(u1.y);
        qv[12]=bflo(u1.z); qv[13]=bfhi(u1.z); qv[14]=bflo(u1.w); qv[15]=bfhi(u1.w);
        float sc[16]; float mx = -1e30f;
        #pragma unroll
        for (int rr = 0; rr < 16; ++rr) {
            const float* kp = rk + rr * 64 + nn * 16;
            float d = 0.f;
            #pragma unroll
            for (int h = 0; h < 16; ++h) d += qv[h] * kp[h];
            d *= 0.25f;
            sc[rr] = d; mx = fmaxf(mx, d);
        }
        float sum = 0.f;
        #pragma unroll
        for (int rr = 0; rr < 16; ++rr) { sc[rr] = expf(sc[rr] - mx); sum += sc[rr]; }
        float inv = 1.0f / sum;
        float o[16];
        #pragma unroll
        for (int h = 0; h < 16; ++h) o[h] = 0.f;
        #pragma unroll
        for (int rr = 0; rr < 16; ++rr) {
            const float* vp = rv + rr * 64 + nn * 16;
            float p = sc[rr];
            #pragma unroll
            for (int h = 0; h < 16; ++h) o[h] += p * vp[h];
        }
        unsigned short* op = bufA + k * 72 + nn * 16;
        #pragma unroll
        for (int h = 0; h < 16; ++h) op[h] = f2bf(o[h] * inv);
    }
    __syncthreads();

    // GEMM4: z = x + lor @ ro -> sXf (in-place)
    head_gemm(bufA, sROT, col, quad, wvid, r);
    #pragma unroll
    for (int u = 0; u < 2; ++u) {
        int tau = wvid + u * 4, mt = tau & 1, nt = tau >> 1;
        #pragma unroll
        for (int reg = 0; reg < 4; ++reg) {
            int row = mt * 16 + quad * 4 + reg;
            if (row < 24) {
                int idx = row * 64 + nt * 16 + col;
                sXf[idx] = sXf[idx] + r[u][reg];
            }
        }
    }
    __syncthreads();

    // LayerNorm stats
    if (t < 24) {
        const float4* zp = (const float4*)(sXf + t * 64);
        float sx_ = 0.f;
        #pragma unroll
        for (int j = 0; j < 16; ++j) {
            float4 v = zp[(j + t) & 15];
            sx_ += v.x + v.y + v.z + v.w;
        }
        float mu = sx_ * (1.0f / 64.0f);
        float vv = 0.f;
        #pragma unroll
        for (int j = 0; j < 16; ++j) {
            float4 v = zp[(j + t) & 15];
            float d0 = v.x - mu, d1 = v.y - mu, d2 = v.z - mu, d3 = v.w - mu;
            vv += d0*d0 + d1*d1 + d2*d2 + d3*d3;
        }
        s_mu[t] = mu;
        s_rs[t] = 1.0f / sqrtf(vv * (1.0f / 64.0f) + EPSF);
    }
    __syncthreads();
    // normalize -> lors bf16 in bufB ; xq staged in parallel
    for (int idx = t; idx < 1536; idx += 256) {
        int k = idx >> 6, e = idx & 63;
        float v = (sXf[idx] - s_mu[k]) * s_rs[k] * lnw[e] + lnb[e];
        bufB[k * 72 + e] = f2bf(v);
    }
    if (t < 128) {
        int q = t >> 6, e = t & 63;
        s_xq[t] = feats[(NSUP + b * 2 + q) * 64 + e] + tags[256 + e];
    }
    __syncthreads();

    // t1[q][s] = r1s[s] . xq[q]
    if (t < 12) {
        int q = t / 6, s = t - q * 6;
        const uint4* rp = (const uint4*)(bufB + (s * 4 + 1) * 72);
        const float* xp = s_xq + q * 64;
        float d = 0.f;
        #pragma unroll
        for (int j = 0; j < 8; ++j) {
            uint4 u = rp[j];
            const float* x = xp + j * 8;
            d += bflo(u.x)*x[0] + bfhi(u.x)*x[1] + bflo(u.y)*x[2] + bfhi(u.y)*x[3]
               + bflo(u.z)*x[4] + bfhi(u.z)*x[5] + bflo(u.w)*x[6] + bfhi(u.w)*x[7];
        }
        s_t1[t] = d;
    }
    __syncthreads();
    // h = w1 xq + sum_s l1s t1 ; ah = gelu(h)
    if (t < 128) {
        int q = t >> 6, e = t & 63;
        const uint4* wp = (const uint4*)(sW1B + e * 72);
        const float* xp = s_xq + q * 64;
        float acc = 0.f;
        #pragma unroll
        for (int j = 0; j < 8; ++j) {
            uint4 u = wp[j];
            const float* x = xp + j * 8;
            acc += bflo(u.x)*x[0] + bfhi(u.x)*x[1] + bflo(u.y)*x[2] + bfhi(u.y)*x[3]
                 + bflo(u.z)*x[4] + bfhi(u.z)*x[5] + bflo(u.w)*x[6] + bfhi(u.w)*x[7];
        }
        #pragma unroll
        for (int s = 0; s < 6; ++s)
            acc += bflo((unsigned)bufB[(s * 4 + 0) * 72 + e]) * s_t1[q * 6 + s];
        s_ah[t] = gelu_f(acc);
    }
    __syncthreads();
    if (t < 12) {
        int q = t / 6, s = t - q * 6;
        const uint4* rp = (const uint4*)(bufB + (s * 4 + 3) * 72);
        const float* xp = s_ah + q * 64;
        float d = 0.f;
        #pragma unroll
        for (int j = 0; j < 8; ++j) {
            uint4 u = rp[j];
            const float* x = xp + j * 8;
            d += bflo(u.x)*x[0] + bfhi(u.x)*x[1] + bflo(u.y)*x[2] + bfhi(u.y)*x[3]
               + bflo(u.z)*x[4] + bfhi(u.z)*x[5] + bflo(u.w)*x[6] + bfhi(u.w)*x[7];
        }
        s_t2[t] = d;
    }
    __syncthreads();
    if (t < 128) {
        int q = t >> 6, e = t & 63;
        const uint4* wp = (const uint4*)(sW2B + e * 72);
        const float* xp = s_ah + q * 64;
        float acc = 0.f;
        #pragma unroll
        for (int j = 0; j < 8; ++j) {
            uint4 u = wp[j];
            const float* x = xp + j * 8;
            acc += bflo(u.x)*x[0] + bfhi(u.x)*x[1] + bflo(u.y)*x[2] + bfhi(u.y)*x[3]
                 + bflo(u.z)*x[4] + bfhi(u.z)*x[5] + bflo(u.w)*x[6] + bfhi(u.w)*x[7];
        }
        #pragma unroll
        for (int s = 0; s < 6; ++s)
            acc += bflo((unsigned)bufB[(s * 4 + 2) * 72 + e]) * s_t2[q * 6 + s];
        s_yp[t] = acc;
    }
    __syncthreads();
    if (t < 4) {
        int q = t >> 1, ll = t & 1;
        const float4* ep = (const float4*)(emb + ll * 64);
        const float4* yp = (const float4*)(s_yp + q * 64);
        float d = 0.f;
        #pragma unroll
        for (int j = 0; j < 16; ++j) {
            float4 a = ep[j], x = yp[j];
            d += a.x*x.x + a.y*x.y + a.z*x.z + a.w*x.w;
        }
        s_lg[t] = d;
    }
    __syncthreads();
    if (t == 0) {
        float lsum = 0.f, corr = 0.f;
        #pragma unroll
        for (int q = 0; q < 2; ++q) {
            float l0 = s_lg[q * 2], l1 = s_lg[q * 2 + 1];
            int lab = qys[b * 2 + q];
            float m = fmaxf(l0, l1);
            float lse = m + logf(expf(l0 - m) + expf(l1 - m));
            lsum += -((lab ? l1 : l0) - lse);
            int pred = (l1 > l0) ? 1 : 0;
            corr += (pred == lab) ? 1.0f : 0.0f;
        }
        part[b] = lsum;
        part[512 + b] = corr;
    }
}

__global__ void __launch_bounds__(256) finalize_kernel(const float* __restrict__ part,
                                                       float* __restrict__ out)
{
    __shared__ float sl[256], sc[256];
    const int t = threadIdx.x;
    sl[t] = part[t] + part[t + 256];
    sc[t] = part[512 + t] + part[768 + t];
    __syncthreads();
    for (int s = 128; s > 0; s >>= 1) {
        if (t < s) { sl[t] += sl[t + s]; sc[t] += sc[t + s]; }
        __syncthreads();
    }
    if (t == 0) {
        float loss = sl[0] * (1.0f / 1024.0f);
        out[0] = loss;
        out[1] = loss;
        out[2] = 0.0f;
        out[3] = sc[0];
        out[4] = 1024.0f;
    }
}

extern "C" void kernel_launch(void* const* d_in, const int* in_sizes, int n_in,
                              void* d_out, int out_size, void* d_ws, size_t ws_size,
                              hipStream_t stream)
{
    (void)in_sizes; (void)n_in; (void)out_size; (void)ws_size;
    const float* sxs  = (const float*)d_in[1];
    const float* qxs  = (const float*)d_in[2];
    const float* c1w  = (const float*)d_in[4];
    const float* c1b  = (const float*)d_in[5];
    const float* bn1  = (const float*)d_in[6];
    const float* c2w  = (const float*)d_in[7];
    const float* c2b  = (const float*)d_in[8];
    const float* bn2  = (const float*)d_in[9];
    const float* c3w  = (const float*)d_in[10];
    const float* c3b  = (const float*)d_in[11];
    const float* bn3  = (const float*)d_in[12];
    const float* c4w  = (const float*)d_in[13];
    const float* c4b  = (const float*)d_in[14];
    const float* bn4  = (const float*)d_in[15];
    const float* lin_w= (const float*)d_in[16];
    const float* emb  = (const float*)d_in[17];
    const float* w1   = (const float*)d_in[18];
    const float* w2   = (const float*)d_in[19];
    const float* tags = (const float*)d_in[20];
    const float* rq   = (const float*)d_in[21];
    const float* rk   = (const float*)d_in[22];
    const float* rv   = (const float*)d_in[23];
    const float* ro   = (const float*)d_in[24];
    const float* lnw  = (const float*)d_in[25];
    const float* lnb  = (const float*)d_in[26];
    const int*   sys  = (const int*)d_in[27];
    const int*   qys  = (const int*)d_in[28];

    float* ws  = (float*)d_ws;
    float* out = (float*)d_out;

    precompute_kernel<<<64, 256, 0, stream>>>(c1w, c1b, bn1, c2w, c2b, bn2,
                                              c3w, c3b, bn3, c4w, c4b, bn4,
                                              w1, w2, rq, ro, ws);
    feats_kernel<<<512, 512, 0, stream>>>(sxs, qxs, lin_w, ws, ws + WS_FEATS);
    head_kernel<<<512, 256, 0, stream>>>(emb, tags, rk, rv, lnw, lnb, sys, qys,
                                         ws, ws + WS_FEATS, ws + WS_PART);
    finalize_kernel<<<1, 256, 0, stream>>>(ws + WS_PART, out);
}